// Round 1
// baseline (1273.727 us; speedup 1.0000x reference)
//
#include <hip/hip_runtime.h>
#include <math.h>

#define D_MODELC 1024
#define K_HEADSC 32
#define ANCHORC 4
#define M_THETAC 4
#define H_DIMC 32
#define TOTALC 2080
#define B_SZC 4
#define L_SEQC 2048
#define NCHUNK 16
#define CHUNK_L (L_SEQC / NCHUNK)  // 128

// ---------------------------------------------------------------------------
// fp32 GEMM: C[M,N] = A[M,K] @ B[K,N], 128x128 tile, 8x8 per thread, BK=8
// ---------------------------------------------------------------------------
__global__ __launch_bounds__(256) void gemm_fp32(
    const float* __restrict__ A, const float* __restrict__ B,
    float* __restrict__ C, int M, int N, int K) {
  __shared__ float As[8][128];
  __shared__ float Bs[8][128];
  const int t = threadIdx.x;
  const int m0 = blockIdx.y * 128;
  const int n0 = blockIdx.x * 128;
  const int arow = t >> 1, acol = (t & 1) * 4;
  const int brow = t >> 5, bcol = (t & 31) * 4;
  const int tm = (t >> 4) * 8, tn = (t & 15) * 8;
  const bool nfull = (n0 + 128 <= N);
  float acc[8][8];
#pragma unroll
  for (int i = 0; i < 8; i++)
#pragma unroll
    for (int j = 0; j < 8; j++) acc[i][j] = 0.f;

  for (int k0 = 0; k0 < K; k0 += 8) {
    float4 av = *(const float4*)(A + (size_t)(m0 + arow) * K + k0 + acol);
    float4 bv;
    if (nfull) {
      bv = *(const float4*)(B + (size_t)(k0 + brow) * N + n0 + bcol);
    } else {
      const float* Bp = B + (size_t)(k0 + brow) * N;
      const int nb = n0 + bcol;
      bv.x = (nb + 0 < N) ? Bp[nb + 0] : 0.f;
      bv.y = (nb + 1 < N) ? Bp[nb + 1] : 0.f;
      bv.z = (nb + 2 < N) ? Bp[nb + 2] : 0.f;
      bv.w = (nb + 3 < N) ? Bp[nb + 3] : 0.f;
    }
    __syncthreads();
    As[acol + 0][arow] = av.x;
    As[acol + 1][arow] = av.y;
    As[acol + 2][arow] = av.z;
    As[acol + 3][arow] = av.w;
    *(float4*)(&Bs[brow][bcol]) = bv;
    __syncthreads();
#pragma unroll
    for (int kk = 0; kk < 8; kk++) {
      float4 a0 = *(float4*)(&As[kk][tm]);
      float4 a1 = *(float4*)(&As[kk][tm + 4]);
      float4 b0 = *(float4*)(&Bs[kk][tn]);
      float4 b1 = *(float4*)(&Bs[kk][tn + 4]);
      float a[8] = {a0.x, a0.y, a0.z, a0.w, a1.x, a1.y, a1.z, a1.w};
      float bb[8] = {b0.x, b0.y, b0.z, b0.w, b1.x, b1.y, b1.z, b1.w};
#pragma unroll
      for (int i = 0; i < 8; i++)
#pragma unroll
        for (int j = 0; j < 8; j++) acc[i][j] = fmaf(a[i], bb[j], acc[i][j]);
    }
  }

#pragma unroll
  for (int i = 0; i < 8; i++) {
    const int m = m0 + tm + i;
    float* Cp = C + (size_t)m * N + n0 + tn;
    if (nfull) {
      float4 c0 = {acc[i][0], acc[i][1], acc[i][2], acc[i][3]};
      float4 c1 = {acc[i][4], acc[i][5], acc[i][6], acc[i][7]};
      *(float4*)(Cp) = c0;
      *(float4*)(Cp + 4) = c1;
    } else {
#pragma unroll
      for (int j = 0; j < 8; j++)
        if (n0 + tn + j < N) Cp[j] = acc[i][j];
    }
  }
}

// ---------------------------------------------------------------------------
// conv (causal depthwise k=4) + split into x_val / silu gate / p_w
// ---------------------------------------------------------------------------
__global__ __launch_bounds__(256) void conv_act(
    const float* __restrict__ z, const float* __restrict__ wconv,
    const float* __restrict__ bconv, const float* __restrict__ score_scale,
    const float* __restrict__ dec_slopes, const float* __restrict__ anc_slopes,
    float* __restrict__ xv, float* __restrict__ gate, float* __restrict__ pw) {
  const int idx = blockIdx.x * 256 + threadIdx.x;
  if (idx >= B_SZC * L_SEQC * TOTALC) return;
  const int c = idx % TOTALC;
  const int bl = idx / TOTALC;
  const int l = bl % L_SEQC;
  float acc = bconv[c];
#pragma unroll
  for (int j = 0; j < 4; j++) {
    const int ls = l - 3 + j;
    if (ls >= 0) acc = fmaf(z[(size_t)(bl - l + ls) * TOTALC + c], wconv[j * TOTALC + c], acc);
  }
  if (c < D_MODELC) {
    xv[(size_t)bl * D_MODELC + c] = acc;
  } else if (c < 2 * D_MODELC) {
    gate[(size_t)bl * D_MODELC + (c - D_MODELC)] = acc / (1.f + __expf(-acc));
  } else {
    const int k = c - 2 * D_MODELC;
    float sv = fminf(fmaxf(score_scale[k] * acc, -20.f), 20.f);
    float p = __expf(sv);
    float tw;
    if (k < K_HEADSC - ANCHORC) {
      float sd = log1pf(__expf(dec_slopes[k]));
      tw = __expf(-sd * (float)(L_SEQC - 1 - l));
    } else {
      float sa = log1pf(__expf(anc_slopes[k - (K_HEADSC - ANCHORC)]));
      tw = __expf(-sa * (float)l);
    }
    pw[(size_t)bl * K_HEADSC + k] = p * tw;
  }
}

// ---------------------------------------------------------------------------
// scan phase 1: per (b,k,chunk) sums of pw*poly*cos/sin (257 channels)
// ---------------------------------------------------------------------------
__global__ __launch_bounds__(256) void scan_partial(
    const float* __restrict__ xv, const float* __restrict__ pw,
    const float* __restrict__ theta, const float* __restrict__ dlog,
    float* __restrict__ cs) {
  const int t = threadIdx.x;
  const int chunk = blockIdx.x % NCHUNK;
  const int bk = blockIdx.x / NCHUNK;
  const int k = bk % K_HEADSC;
  const int b = bk / K_HEADSC;
  __shared__ float theta_s[128];
  __shared__ float xv_s[32];
  __shared__ float pw_s;
  if (t < 128) theta_s[t] = theta[k * 128 + t];
  const float d0 = dlog[0], d1 = dlog[1], d2 = dlog[2];
  const float mx = fmaxf(d0, fmaxf(d1, d2));
  const float e0 = __expf(d0 - mx), e1 = __expf(d1 - mx), e2 = __expf(d2 - mx);
  const float inv_sum = 1.f / (e0 + e1 + e2);
  const float w0 = e0 * inv_sum, w1 = e1 * inv_sum, w2 = e2 * inv_sum;
  const int c = t & 127;
  const int h = c >> 2;
  const bool is_re = (t < 128);
  float acc = 0.f, den_acc = 0.f;
  const int l0 = chunk * CHUNK_L;
  for (int li = 0; li < CHUNK_L; ++li) {
    const int l = l0 + li;
    __syncthreads();
    if (t < 32) xv_s[t] = xv[(size_t)(b * L_SEQC + l) * D_MODELC + k * H_DIMC + t];
    if (t == 32) pw_s = pw[(size_t)(b * L_SEQC + l) * K_HEADSC + k];
    __syncthreads();
    const float pwv = pw_s;
    const float xx = xv_s[h];
    const float phi = xx * theta_s[c];
    const float poly = w0 + w1 * xx - w2 * xx * xx;
    const float tr = is_re ? __cosf(phi) : __sinf(phi);
    acc = fmaf(pwv * poly, tr, acc);
    den_acc += pwv;
  }
  const size_t base = (size_t)blockIdx.x * 257;
  cs[base + t] = acc;
  if (t == 0) cs[base + 256] = den_acc;
}

// ---------------------------------------------------------------------------
// scan phase 2: exclusive scan over the 16 chunk-sums per (b,k,channel)
// ---------------------------------------------------------------------------
__global__ __launch_bounds__(256) void scan_chunks(float* __restrict__ cs) {
  const int idx = blockIdx.x * 256 + threadIdx.x;
  if (idx >= B_SZC * K_HEADSC * 257) return;
  const int c = idx % 257;
  const int bk = idx / 257;
  float s = 0.f;
  for (int ch = 0; ch < NCHUNK; ++ch) {
    const size_t p = (size_t)(bk * NCHUNK + ch) * 257 + c;
    const float v = cs[p];
    cs[p] = s;
    s += v;
  }
}

// ---------------------------------------------------------------------------
// scan phase 3: apply offsets, 1/den, RMS norm, 256->32 projection, gate
// ---------------------------------------------------------------------------
__global__ __launch_bounds__(256) void scan_apply(
    const float* __restrict__ xv, const float* __restrict__ pw,
    const float* __restrict__ gate, const float* __restrict__ theta,
    const float* __restrict__ dlog, const float* __restrict__ nsc,
    const float* __restrict__ W_re, const float* __restrict__ W_im,
    const float* __restrict__ cs, float* __restrict__ ypre) {
  const int t = threadIdx.x;
  const int chunk = blockIdx.x % NCHUNK;
  const int bk = blockIdx.x / NCHUNK;
  const int k = bk % K_HEADSC;
  const int b = bk / K_HEADSC;
  __shared__ float Wc_s[256 * 32];
  __shared__ float theta_s[128];
  __shared__ float xv_s[32];
  __shared__ float vn_s[256];
  __shared__ float part_s[256];
  __shared__ float wred[4];
  __shared__ float pw_sh;
  for (int i = t; i < 256 * 32; i += 256) {
    const int cc = i >> 5, hh = i & 31;
    const float wv = (cc < 128) ? W_re[cc * 32 + hh] : W_im[(cc - 128) * 32 + hh];
    Wc_s[i] = wv * nsc[cc];
  }
  if (t < 128) theta_s[t] = theta[k * 128 + t];
  const float d0 = dlog[0], d1 = dlog[1], d2 = dlog[2];
  const float mx = fmaxf(d0, fmaxf(d1, d2));
  const float e0 = __expf(d0 - mx), e1 = __expf(d1 - mx), e2 = __expf(d2 - mx);
  const float inv_sum = 1.f / (e0 + e1 + e2);
  const float w0 = e0 * inv_sum, w1 = e1 * inv_sum, w2 = e2 * inv_sum;
  const size_t base = (size_t)blockIdx.x * 257;
  const float off_c = cs[base + t];
  const float den_off = cs[base + 256];
  const int c = t & 127;
  const int h = c >> 2;
  const bool is_re = (t < 128);
  const int g = t >> 5;
  const int ho = t & 31;
  __syncthreads();
  float wreg[32];
#pragma unroll
  for (int j = 0; j < 32; j++) wreg[j] = Wc_s[(g * 32 + j) * 32 + ho];
  float acc = 0.f, den_acc = 0.f;
  const int l0 = chunk * CHUNK_L;
  for (int li = 0; li < CHUNK_L; ++li) {
    const int l = l0 + li;
    __syncthreads();  // protect xv_s/vn_s overwrite vs prev iteration readers
    if (t < 32) xv_s[t] = xv[(size_t)(b * L_SEQC + l) * D_MODELC + k * H_DIMC + t];
    if (t == 32) pw_sh = pw[(size_t)(b * L_SEQC + l) * K_HEADSC + k];
    __syncthreads();
    const float pwv = pw_sh;
    den_acc += pwv;
    const float inv = 1.f / fmaxf(den_off + den_acc, 1e-4f);
    const float xx = xv_s[h];
    const float phi = xx * theta_s[c];
    const float poly = w0 + w1 * xx - w2 * xx * xx;
    const float tr = is_re ? __cosf(phi) : __sinf(phi);
    acc = fmaf(pwv * poly, tr, acc);
    const float v = (off_c + acc) * inv;
    vn_s[t] = v;
    float sq = v * v;
#pragma unroll
    for (int off = 32; off >= 1; off >>= 1) sq += __shfl_down(sq, off, 64);
    if ((t & 63) == 0) wred[t >> 6] = sq;
    __syncthreads();
    const float total = wred[0] + wred[1] + wred[2] + wred[3];
    const float rsq = rsqrtf(total * (1.f / 256.f) + 1e-5f);
    float part = 0.f;
#pragma unroll
    for (int j = 0; j < 32; j += 4) {
      float4 v4 = *(float4*)(&vn_s[g * 32 + j]);
      part = fmaf(v4.x, wreg[j + 0], part);
      part = fmaf(v4.y, wreg[j + 1], part);
      part = fmaf(v4.z, wreg[j + 2], part);
      part = fmaf(v4.w, wreg[j + 3], part);
    }
    part_s[t] = part;
    __syncthreads();
    if (t < 32) {
      float y = 0.f;
#pragma unroll
      for (int gg = 0; gg < 8; gg++) y += part_s[gg * 32 + t];
      y *= rsq;
      const size_t oi = (size_t)(b * L_SEQC + l) * D_MODELC + k * H_DIMC + t;
      ypre[oi] = y * gate[oi];
    }
  }
}

// ---------------------------------------------------------------------------
extern "C" void kernel_launch(void* const* d_in, const int* in_sizes, int n_in,
                              void* d_out, int out_size, void* d_ws, size_t ws_size,
                              hipStream_t stream) {
  const float* x       = (const float*)d_in[0];
  const float* W_in    = (const float*)d_in[1];
  const float* w_conv  = (const float*)d_in[2];
  const float* b_conv  = (const float*)d_in[3];
  const float* theta   = (const float*)d_in[4];
  const float* dec     = (const float*)d_in[5];
  const float* anc     = (const float*)d_in[6];
  const float* score   = (const float*)d_in[7];
  const float* dlog    = (const float*)d_in[8];
  const float* nsc     = (const float*)d_in[9];
  const float* W_re    = (const float*)d_in[10];
  const float* W_im    = (const float*)d_in[11];
  const float* W_out   = (const float*)d_in[12];
  float* out = (float*)d_out;

  float* ws   = (float*)d_ws;
  float* z    = ws;                      // 17,039,360 floats (B*L*2080)
  float* ypre = ws;                      // aliases z (z dead after conv_act)
  float* xv   = ws + 17039360;           // 8,388,608
  float* gate = xv + 8388608;            // 8,388,608
  float* pwb  = gate + 8388608;          // 262,144
  float* cs   = pwb + 262144;            // 526,336 (B*K*NCHUNK*257)

  dim3 blk(256);
  const int M = B_SZC * L_SEQC;  // 8192

  gemm_fp32<<<dim3((TOTALC + 127) / 128, M / 128), blk, 0, stream>>>(
      x, W_in, z, M, TOTALC, D_MODELC);
  conv_act<<<dim3((B_SZC * L_SEQC * TOTALC) / 256), blk, 0, stream>>>(
      z, w_conv, b_conv, score, dec, anc, xv, gate, pwb);
  scan_partial<<<dim3(B_SZC * K_HEADSC * NCHUNK), blk, 0, stream>>>(
      xv, pwb, theta, dlog, cs);
  scan_chunks<<<dim3((B_SZC * K_HEADSC * 257 + 255) / 256), blk, 0, stream>>>(cs);
  scan_apply<<<dim3(B_SZC * K_HEADSC * NCHUNK), blk, 0, stream>>>(
      xv, pwb, gate, theta, dlog, nsc, W_re, W_im, cs, ypre);
  gemm_fp32<<<dim3(D_MODELC / 128, M / 128), blk, 0, stream>>>(
      ypre, W_out, out, M, D_MODELC, D_MODELC);
}

// Round 2
// 689.899 us; speedup vs baseline: 1.8462x; 1.8462x over previous
//
#include <hip/hip_runtime.h>
#include <math.h>

#define D_MODELC 1024
#define K_HEADSC 32
#define ANCHORC 4
#define M_THETAC 4
#define H_DIMC 32
#define TOTALC 2080
#define B_SZC 4
#define L_SEQC 2048
#define NCHUNK 16
#define CHUNK_L (L_SEQC / NCHUNK)  // 128

typedef unsigned short ushort_t;
typedef __attribute__((ext_vector_type(8))) short short8;
typedef __attribute__((ext_vector_type(4))) float f32x4;

__device__ __forceinline__ ushort_t f2bf(float f) {
  union { float f; unsigned u; } v; v.f = f;
  unsigned u = v.u;
  return (ushort_t)((u + 0x7fffu + ((u >> 16) & 1u)) >> 16);
}
__device__ __forceinline__ float bf2f(ushort_t b) {
  union { unsigned u; float f; } v; v.u = ((unsigned)b) << 16;
  return v.f;
}

// ---------------------------------------------------------------------------
// fp32 -> bf16 elementwise (n divisible by 1024)
// ---------------------------------------------------------------------------
__global__ __launch_bounds__(256) void cvt_bf16(
    const float* __restrict__ in, ushort_t* __restrict__ out, int n) {
  const int i = (blockIdx.x * 256 + threadIdx.x) * 4;
  if (i >= n) return;
  float4 v = *(const float4*)(in + i);
  ushort_t o0 = f2bf(v.x), o1 = f2bf(v.y), o2 = f2bf(v.z), o3 = f2bf(v.w);
  ushort4 o = {o0, o1, o2, o3};
  *(ushort4*)(out + i) = o;
}

// ---------------------------------------------------------------------------
// fp32 [K,N] -> bf16 transposed [Npad,K], zero-padding rows N..Npad-1
// grid (Npad/32, K/32), block 256
// ---------------------------------------------------------------------------
__global__ __launch_bounds__(256) void cvt_t_bf16(
    const float* __restrict__ W, ushort_t* __restrict__ Wt,
    int K, int N, int Npad) {
  __shared__ float tile[32][33];
  const int n0 = blockIdx.x * 32, k0 = blockIdx.y * 32;
  const int tx = threadIdx.x & 31, ty = threadIdx.x >> 5;  // ty: 0..7
#pragma unroll
  for (int i = 0; i < 4; i++) {
    const int kk = ty + i * 8;
    const int n = n0 + tx;
    tile[kk][tx] = (n < N) ? W[(size_t)(k0 + kk) * N + n] : 0.f;
  }
  __syncthreads();
#pragma unroll
  for (int i = 0; i < 4; i++) {
    const int nn = ty + i * 8;
    Wt[(size_t)(n0 + nn) * K + k0 + tx] = f2bf(tile[tx][nn]);
  }
}

// ---------------------------------------------------------------------------
// bf16 MFMA GEMM: C[M,Nout] = A[M,K] @ Bt[N,K]^T   (fp32 out)
// 128x128 tile, BK=32, 4 waves (2x2), each wave 64x64 via 4x4 16x16x32 MFMA.
// global_load_lds width-16 staging (m97 structure).
// ---------------------------------------------------------------------------
__global__ __launch_bounds__(256) void gemm_bf16_bt(
    const ushort_t* __restrict__ A, const ushort_t* __restrict__ Bt,
    float* __restrict__ C, int M, int K, int Nout) {
  __shared__ ushort_t As[128 * 32];
  __shared__ ushort_t Bs[128 * 32];
  const int t = threadIdx.x;
  const int wave = t >> 6, lane = t & 63;
  const int m0 = blockIdx.y * 128, n0 = blockIdx.x * 128;
  const int m0w = (wave >> 1) * 64, n0w = (wave & 1) * 64;
  const int quad = lane >> 4, r16 = lane & 15;

  f32x4 acc[4][4] = {};

  for (int k0 = 0; k0 < K; k0 += 32) {
    __syncthreads();
#pragma unroll
    for (int i = 0; i < 2; i++) {
      const int seg = wave * 2 + i;                 // 0..7, wave-uniform
      const int byteoff = seg * 1024 + lane * 16;   // byte offset in 8KB tile
      const int row = byteoff >> 6;                 // 64 B per row (32 bf16)
      const int col = (byteoff & 63) >> 1;
      const ushort_t* gpA = A + (size_t)(m0 + row) * K + k0 + col;
      const ushort_t* gpB = Bt + (size_t)(n0 + row) * K + k0 + col;
      __builtin_amdgcn_global_load_lds(
          (const __attribute__((address_space(1))) void*)gpA,
          (__attribute__((address_space(3))) void*)(As + seg * 512), 16, 0, 0);
      __builtin_amdgcn_global_load_lds(
          (const __attribute__((address_space(1))) void*)gpB,
          (__attribute__((address_space(3))) void*)(Bs + seg * 512), 16, 0, 0);
    }
    __syncthreads();
    short8 af[4], bfv[4];
#pragma unroll
    for (int i = 0; i < 4; i++)
      af[i] = *(const short8*)(As + (m0w + i * 16 + r16) * 32 + quad * 8);
#pragma unroll
    for (int j = 0; j < 4; j++)
      bfv[j] = *(const short8*)(Bs + (n0w + j * 16 + r16) * 32 + quad * 8);
#pragma unroll
    for (int i = 0; i < 4; i++)
#pragma unroll
      for (int j = 0; j < 4; j++)
        acc[i][j] = __builtin_amdgcn_mfma_f32_16x16x32_bf16(
            af[i], bfv[j], acc[i][j], 0, 0, 0);
  }

#pragma unroll
  for (int i = 0; i < 4; i++) {
#pragma unroll
    for (int j = 0; j < 4; j++) {
      const int n = n0 + n0w + j * 16 + r16;
      if (n >= Nout) continue;
#pragma unroll
      for (int r = 0; r < 4; r++) {
        const int m = m0 + m0w + i * 16 + quad * 4 + r;
        C[(size_t)m * Nout + n] = acc[i][j][r];
      }
    }
  }
}

// ---------------------------------------------------------------------------
// conv (causal depthwise k=4) + split into x_val / silu gate (bf16) / p_w
// ---------------------------------------------------------------------------
__global__ __launch_bounds__(256) void conv_act(
    const float* __restrict__ z, const float* __restrict__ wconv,
    const float* __restrict__ bconv, const float* __restrict__ score_scale,
    const float* __restrict__ dec_slopes, const float* __restrict__ anc_slopes,
    ushort_t* __restrict__ xv, ushort_t* __restrict__ gate,
    float* __restrict__ pw) {
  const int idx = blockIdx.x * 256 + threadIdx.x;
  if (idx >= B_SZC * L_SEQC * TOTALC) return;
  const int c = idx % TOTALC;
  const int bl = idx / TOTALC;
  const int l = bl % L_SEQC;
  float acc = bconv[c];
#pragma unroll
  for (int j = 0; j < 4; j++) {
    const int ls = l - 3 + j;
    if (ls >= 0) acc = fmaf(z[(size_t)(bl - l + ls) * TOTALC + c], wconv[j * TOTALC + c], acc);
  }
  if (c < D_MODELC) {
    xv[(size_t)bl * D_MODELC + c] = f2bf(acc);
  } else if (c < 2 * D_MODELC) {
    gate[(size_t)bl * D_MODELC + (c - D_MODELC)] = f2bf(acc / (1.f + __expf(-acc)));
  } else {
    const int k = c - 2 * D_MODELC;
    float sv = fminf(fmaxf(score_scale[k] * acc, -20.f), 20.f);
    float p = __expf(sv);
    float tw;
    if (k < K_HEADSC - ANCHORC) {
      float sd = log1pf(__expf(dec_slopes[k]));
      tw = __expf(-sd * (float)(L_SEQC - 1 - l));
    } else {
      float sa = log1pf(__expf(anc_slopes[k - (K_HEADSC - ANCHORC)]));
      tw = __expf(-sa * (float)l);
    }
    pw[(size_t)bl * K_HEADSC + k] = p * tw;
  }
}

// ---------------------------------------------------------------------------
// scan phase 1: per (b,k,chunk) sums of pw*poly*cos/sin (257 channels)
// ---------------------------------------------------------------------------
__global__ __launch_bounds__(256) void scan_partial(
    const ushort_t* __restrict__ xv, const float* __restrict__ pw,
    const float* __restrict__ theta, const float* __restrict__ dlog,
    float* __restrict__ cs) {
  const int t = threadIdx.x;
  const int chunk = blockIdx.x % NCHUNK;
  const int bk = blockIdx.x / NCHUNK;
  const int k = bk % K_HEADSC;
  const int b = bk / K_HEADSC;
  __shared__ float theta_s[128];
  __shared__ float xv_s[32];
  __shared__ float pw_s;
  if (t < 128) theta_s[t] = theta[k * 128 + t];
  const float d0 = dlog[0], d1 = dlog[1], d2 = dlog[2];
  const float mx = fmaxf(d0, fmaxf(d1, d2));
  const float e0 = __expf(d0 - mx), e1 = __expf(d1 - mx), e2 = __expf(d2 - mx);
  const float inv_sum = 1.f / (e0 + e1 + e2);
  const float w0 = e0 * inv_sum, w1 = e1 * inv_sum, w2 = e2 * inv_sum;
  const int c = t & 127;
  const int h = c >> 2;
  const bool is_re = (t < 128);
  float acc = 0.f, den_acc = 0.f;
  const int l0 = chunk * CHUNK_L;
  for (int li = 0; li < CHUNK_L; ++li) {
    const int l = l0 + li;
    __syncthreads();
    if (t < 32) xv_s[t] = bf2f(xv[(size_t)(b * L_SEQC + l) * D_MODELC + k * H_DIMC + t]);
    if (t == 32) pw_s = pw[(size_t)(b * L_SEQC + l) * K_HEADSC + k];
    __syncthreads();
    const float pwv = pw_s;
    const float xx = xv_s[h];
    const float phi = xx * theta_s[c];
    const float poly = w0 + w1 * xx - w2 * xx * xx;
    const float tr = is_re ? __cosf(phi) : __sinf(phi);
    acc = fmaf(pwv * poly, tr, acc);
    den_acc += pwv;
  }
  const size_t base = (size_t)blockIdx.x * 257;
  cs[base + t] = acc;
  if (t == 0) cs[base + 256] = den_acc;
}

// ---------------------------------------------------------------------------
// scan phase 2: exclusive scan over the 16 chunk-sums per (b,k,channel)
// ---------------------------------------------------------------------------
__global__ __launch_bounds__(256) void scan_chunks(float* __restrict__ cs) {
  const int idx = blockIdx.x * 256 + threadIdx.x;
  if (idx >= B_SZC * K_HEADSC * 257) return;
  const int c = idx % 257;
  const int bk = idx / 257;
  float s = 0.f;
  for (int ch = 0; ch < NCHUNK; ++ch) {
    const size_t p = (size_t)(bk * NCHUNK + ch) * 257 + c;
    const float v = cs[p];
    cs[p] = s;
    s += v;
  }
}

// ---------------------------------------------------------------------------
// scan phase 3: apply offsets, 1/den, RMS norm, 256->32 projection, gate
// writes ypre as bf16
// ---------------------------------------------------------------------------
__global__ __launch_bounds__(256) void scan_apply(
    const ushort_t* __restrict__ xv, const float* __restrict__ pw,
    const ushort_t* __restrict__ gate, const float* __restrict__ theta,
    const float* __restrict__ dlog, const float* __restrict__ nsc,
    const float* __restrict__ W_re, const float* __restrict__ W_im,
    const float* __restrict__ cs, ushort_t* __restrict__ ypre) {
  const int t = threadIdx.x;
  const int chunk = blockIdx.x % NCHUNK;
  const int bk = blockIdx.x / NCHUNK;
  const int k = bk % K_HEADSC;
  const int b = bk / K_HEADSC;
  __shared__ float Wc_s[256 * 32];
  __shared__ float theta_s[128];
  __shared__ float xv_s[32];
  __shared__ float vn_s[256];
  __shared__ float part_s[256];
  __shared__ float wred[4];
  __shared__ float pw_sh;
  for (int i = t; i < 256 * 32; i += 256) {
    const int cc = i >> 5, hh = i & 31;
    const float wv = (cc < 128) ? W_re[cc * 32 + hh] : W_im[(cc - 128) * 32 + hh];
    Wc_s[i] = wv * nsc[cc];
  }
  if (t < 128) theta_s[t] = theta[k * 128 + t];
  const float d0 = dlog[0], d1 = dlog[1], d2 = dlog[2];
  const float mx = fmaxf(d0, fmaxf(d1, d2));
  const float e0 = __expf(d0 - mx), e1 = __expf(d1 - mx), e2 = __expf(d2 - mx);
  const float inv_sum = 1.f / (e0 + e1 + e2);
  const float w0 = e0 * inv_sum, w1 = e1 * inv_sum, w2 = e2 * inv_sum;
  const size_t base = (size_t)blockIdx.x * 257;
  const float off_c = cs[base + t];
  const float den_off = cs[base + 256];
  const int c = t & 127;
  const int h = c >> 2;
  const bool is_re = (t < 128);
  const int g = t >> 5;
  const int ho = t & 31;
  __syncthreads();
  float wreg[32];
#pragma unroll
  for (int j = 0; j < 32; j++) wreg[j] = Wc_s[(g * 32 + j) * 32 + ho];
  float acc = 0.f, den_acc = 0.f;
  const int l0 = chunk * CHUNK_L;
  for (int li = 0; li < CHUNK_L; ++li) {
    const int l = l0 + li;
    __syncthreads();
    if (t < 32) xv_s[t] = bf2f(xv[(size_t)(b * L_SEQC + l) * D_MODELC + k * H_DIMC + t]);
    if (t == 32) pw_sh = pw[(size_t)(b * L_SEQC + l) * K_HEADSC + k];
    __syncthreads();
    const float pwv = pw_sh;
    den_acc += pwv;
    const float inv = 1.f / fmaxf(den_off + den_acc, 1e-4f);
    const float xx = xv_s[h];
    const float phi = xx * theta_s[c];
    const float poly = w0 + w1 * xx - w2 * xx * xx;
    const float tr = is_re ? __cosf(phi) : __sinf(phi);
    acc = fmaf(pwv * poly, tr, acc);
    const float v = (off_c + acc) * inv;
    vn_s[t] = v;
    float sq = v * v;
#pragma unroll
    for (int off = 32; off >= 1; off >>= 1) sq += __shfl_down(sq, off, 64);
    if ((t & 63) == 0) wred[t >> 6] = sq;
    __syncthreads();
    const float total = wred[0] + wred[1] + wred[2] + wred[3];
    const float rsq = rsqrtf(total * (1.f / 256.f) + 1e-5f);
    float part = 0.f;
#pragma unroll
    for (int j = 0; j < 32; j += 4) {
      float4 v4 = *(float4*)(&vn_s[g * 32 + j]);
      part = fmaf(v4.x, wreg[j + 0], part);
      part = fmaf(v4.y, wreg[j + 1], part);
      part = fmaf(v4.z, wreg[j + 2], part);
      part = fmaf(v4.w, wreg[j + 3], part);
    }
    part_s[t] = part;
    __syncthreads();
    if (t < 32) {
      float y = 0.f;
#pragma unroll
      for (int gg = 0; gg < 8; gg++) y += part_s[gg * 32 + t];
      y *= rsq;
      const size_t oi = (size_t)(b * L_SEQC + l) * D_MODELC + k * H_DIMC + t;
      ypre[oi] = f2bf(y * bf2f(gate[oi]));
    }
  }
}

// ---------------------------------------------------------------------------
extern "C" void kernel_launch(void* const* d_in, const int* in_sizes, int n_in,
                              void* d_out, int out_size, void* d_ws, size_t ws_size,
                              hipStream_t stream) {
  const float* x       = (const float*)d_in[0];
  const float* W_in    = (const float*)d_in[1];
  const float* w_conv  = (const float*)d_in[2];
  const float* b_conv  = (const float*)d_in[3];
  const float* theta   = (const float*)d_in[4];
  const float* dec     = (const float*)d_in[5];
  const float* anc     = (const float*)d_in[6];
  const float* score   = (const float*)d_in[7];
  const float* dlog    = (const float*)d_in[8];
  const float* nsc     = (const float*)d_in[9];
  const float* W_re    = (const float*)d_in[10];
  const float* W_im    = (const float*)d_in[11];
  const float* W_out   = (const float*)d_in[12];
  float* out = (float*)d_out;

  char* wsb = (char*)d_ws;
  float*    z    = (float*)(wsb + 0);             // 8192*2080*4 = 68,157,440
  ushort_t* ypre = (ushort_t*)(wsb + 0);          // alias (z dead), 16,777,216
  ushort_t* WtO  = (ushort_t*)(wsb + 16777216);   // alias in z region, 2,097,152
  ushort_t* xv   = (ushort_t*)(wsb + 68157440);   // 16,777,216
  ushort_t* gate = (ushort_t*)(wsb + 84934656);   // 16,777,216
  float*    pwb  = (float*)(wsb + 101711872);     // 1,048,576
  float*    cs   = (float*)(wsb + 102760448);     // 2,105,344
  ushort_t* xb   = (ushort_t*)(wsb + 104865792);  // 16,777,216
  ushort_t* WtI  = (ushort_t*)(wsb + 121643008);  // 2176*1024*2 = 4,456,448
  // total 126,099,456 B

  dim3 blk(256);
  const int M = B_SZC * L_SEQC;  // 8192

  cvt_bf16<<<dim3(M * D_MODELC / 1024), blk, 0, stream>>>(x, xb, M * D_MODELC);
  cvt_t_bf16<<<dim3(2176 / 32, D_MODELC / 32), blk, 0, stream>>>(
      W_in, WtI, D_MODELC, TOTALC, 2176);
  gemm_bf16_bt<<<dim3(2176 / 128, M / 128), blk, 0, stream>>>(
      xb, WtI, z, M, D_MODELC, TOTALC);
  conv_act<<<dim3((B_SZC * L_SEQC * TOTALC) / 256), blk, 0, stream>>>(
      z, w_conv, b_conv, score, dec, anc, xv, gate, pwb);
  // z dead from here; WtO/ypre alias its region
  cvt_t_bf16<<<dim3(D_MODELC / 32, D_MODELC / 32), blk, 0, stream>>>(
      W_out, WtO, D_MODELC, D_MODELC, D_MODELC);
  scan_partial<<<dim3(B_SZC * K_HEADSC * NCHUNK), blk, 0, stream>>>(
      xv, pwb, theta, dlog, cs);
  scan_chunks<<<dim3((B_SZC * K_HEADSC * 257 + 255) / 256), blk, 0, stream>>>(cs);
  scan_apply<<<dim3(B_SZC * K_HEADSC * NCHUNK), blk, 0, stream>>>(
      xv, pwb, gate, theta, dlog, nsc, W_re, W_im, cs, ypre);
  gemm_bf16_bt<<<dim3(D_MODELC / 128, M / 128), blk, 0, stream>>>(
      ypre, WtO, out, M, D_MODELC, D_MODELC);
}

// Round 3
// 388.644 us; speedup vs baseline: 3.2774x; 1.7751x over previous
//
#include <hip/hip_runtime.h>
#include <math.h>

#define D_MODELC 1024
#define K_HEADSC 32
#define ANCHORC 4
#define M_THETAC 4
#define H_DIMC 32
#define TOTALC 2080
#define B_SZC 4
#define L_SEQC 2048
#define NCHUNK 32
#define CHUNK_L (L_SEQC / NCHUNK)  // 64

typedef unsigned short ushort_t;
typedef __attribute__((ext_vector_type(8))) short short8;
typedef __attribute__((ext_vector_type(4))) float f32x4;

__device__ __forceinline__ ushort_t f2bf(float f) {
  union { float f; unsigned u; } v; v.f = f;
  unsigned u = v.u;
  return (ushort_t)((u + 0x7fffu + ((u >> 16) & 1u)) >> 16);
}
__device__ __forceinline__ float bf2f(ushort_t b) {
  union { unsigned u; float f; } v; v.u = ((unsigned)b) << 16;
  return v.f;
}

// ---------------------------------------------------------------------------
// fp32 -> bf16 elementwise (n divisible by 1024)
// ---------------------------------------------------------------------------
__global__ __launch_bounds__(256) void cvt_bf16(
    const float* __restrict__ in, ushort_t* __restrict__ out, int n) {
  const int i = (blockIdx.x * 256 + threadIdx.x) * 4;
  if (i >= n) return;
  float4 v = *(const float4*)(in + i);
  ushort_t o0 = f2bf(v.x), o1 = f2bf(v.y), o2 = f2bf(v.z), o3 = f2bf(v.w);
  ushort4 o = {o0, o1, o2, o3};
  *(ushort4*)(out + i) = o;
}

// ---------------------------------------------------------------------------
// fp32 [K,N] -> bf16 transposed [Npad,K], zero-padding rows N..Npad-1
// ---------------------------------------------------------------------------
__global__ __launch_bounds__(256) void cvt_t_bf16(
    const float* __restrict__ W, ushort_t* __restrict__ Wt,
    int K, int N, int Npad) {
  __shared__ float tile[32][33];
  const int n0 = blockIdx.x * 32, k0 = blockIdx.y * 32;
  const int tx = threadIdx.x & 31, ty = threadIdx.x >> 5;
#pragma unroll
  for (int i = 0; i < 4; i++) {
    const int kk = ty + i * 8;
    const int n = n0 + tx;
    tile[kk][tx] = (n < N) ? W[(size_t)(k0 + kk) * N + n] : 0.f;
  }
  __syncthreads();
#pragma unroll
  for (int i = 0; i < 4; i++) {
    const int nn = ty + i * 8;
    Wt[(size_t)(n0 + nn) * K + k0 + tx] = f2bf(tile[tx][nn]);
  }
}

// ---------------------------------------------------------------------------
// bf16 MFMA GEMM: C[M,Nout] = A[M,K] @ Bt[N,K]^T   (fp32 out)
// ---------------------------------------------------------------------------
__global__ __launch_bounds__(256) void gemm_bf16_bt(
    const ushort_t* __restrict__ A, const ushort_t* __restrict__ Bt,
    float* __restrict__ C, int M, int K, int Nout) {
  __shared__ ushort_t As[128 * 32];
  __shared__ ushort_t Bs[128 * 32];
  const int t = threadIdx.x;
  const int wave = t >> 6, lane = t & 63;
  const int m0 = blockIdx.y * 128, n0 = blockIdx.x * 128;
  const int m0w = (wave >> 1) * 64, n0w = (wave & 1) * 64;
  const int quad = lane >> 4, r16 = lane & 15;

  f32x4 acc[4][4] = {};

  for (int k0 = 0; k0 < K; k0 += 32) {
    __syncthreads();
#pragma unroll
    for (int i = 0; i < 2; i++) {
      const int seg = wave * 2 + i;
      const int byteoff = seg * 1024 + lane * 16;
      const int row = byteoff >> 6;
      const int col = (byteoff & 63) >> 1;
      const ushort_t* gpA = A + (size_t)(m0 + row) * K + k0 + col;
      const ushort_t* gpB = Bt + (size_t)(n0 + row) * K + k0 + col;
      __builtin_amdgcn_global_load_lds(
          (const __attribute__((address_space(1))) void*)gpA,
          (__attribute__((address_space(3))) void*)(As + seg * 512), 16, 0, 0);
      __builtin_amdgcn_global_load_lds(
          (const __attribute__((address_space(1))) void*)gpB,
          (__attribute__((address_space(3))) void*)(Bs + seg * 512), 16, 0, 0);
    }
    __syncthreads();
    short8 af[4], bfv[4];
#pragma unroll
    for (int i = 0; i < 4; i++)
      af[i] = *(const short8*)(As + (m0w + i * 16 + r16) * 32 + quad * 8);
#pragma unroll
    for (int j = 0; j < 4; j++)
      bfv[j] = *(const short8*)(Bs + (n0w + j * 16 + r16) * 32 + quad * 8);
#pragma unroll
    for (int i = 0; i < 4; i++)
#pragma unroll
      for (int j = 0; j < 4; j++)
        acc[i][j] = __builtin_amdgcn_mfma_f32_16x16x32_bf16(
            af[i], bfv[j], acc[i][j], 0, 0, 0);
  }

#pragma unroll
  for (int i = 0; i < 4; i++) {
#pragma unroll
    for (int j = 0; j < 4; j++) {
      const int n = n0 + n0w + j * 16 + r16;
      if (n >= Nout) continue;
#pragma unroll
      for (int r = 0; r < 4; r++) {
        const int m = m0 + m0w + i * 16 + quad * 4 + r;
        C[(size_t)m * Nout + n] = acc[i][j][r];
      }
    }
  }
}

// ---------------------------------------------------------------------------
// conv (causal depthwise k=4) + split into x_val / silu gate (bf16) / p_w
// ---------------------------------------------------------------------------
__global__ __launch_bounds__(256) void conv_act(
    const float* __restrict__ z, const float* __restrict__ wconv,
    const float* __restrict__ bconv, const float* __restrict__ score_scale,
    const float* __restrict__ dec_slopes, const float* __restrict__ anc_slopes,
    ushort_t* __restrict__ xv, ushort_t* __restrict__ gate,
    float* __restrict__ pw) {
  const int idx = blockIdx.x * 256 + threadIdx.x;
  if (idx >= B_SZC * L_SEQC * TOTALC) return;
  const int c = idx % TOTALC;
  const int bl = idx / TOTALC;
  const int l = bl % L_SEQC;
  float acc = bconv[c];
#pragma unroll
  for (int j = 0; j < 4; j++) {
    const int ls = l - 3 + j;
    if (ls >= 0) acc = fmaf(z[(size_t)(bl - l + ls) * TOTALC + c], wconv[j * TOTALC + c], acc);
  }
  if (c < D_MODELC) {
    xv[(size_t)bl * D_MODELC + c] = f2bf(acc);
  } else if (c < 2 * D_MODELC) {
    gate[(size_t)bl * D_MODELC + (c - D_MODELC)] = f2bf(acc / (1.f + __expf(-acc)));
  } else {
    const int k = c - 2 * D_MODELC;
    float sv = fminf(fmaxf(score_scale[k] * acc, -20.f), 20.f);
    float p = __expf(sv);
    float tw;
    if (k < K_HEADSC - ANCHORC) {
      float sd = log1pf(__expf(dec_slopes[k]));
      tw = __expf(-sd * (float)(L_SEQC - 1 - l));
    } else {
      float sa = log1pf(__expf(anc_slopes[k - (K_HEADSC - ANCHORC)]));
      tw = __expf(-sa * (float)l);
    }
    pw[(size_t)bl * K_HEADSC + k] = p * tw;
  }
}

// ---------------------------------------------------------------------------
// scan phase 1: per (b,k,chunk) sums of pw*poly*cos/sin (257 channels)
// Barrier-free main loop: preload xv (transposed) + pw once.
// ---------------------------------------------------------------------------
__global__ __launch_bounds__(256) void scan_partial(
    const ushort_t* __restrict__ xv, const float* __restrict__ pw,
    const float* __restrict__ theta, const float* __restrict__ dlog,
    float* __restrict__ cs) {
  const int t = threadIdx.x;
  const int chunk = blockIdx.x % NCHUNK;
  const int bk = blockIdx.x / NCHUNK;
  const int k = bk % K_HEADSC;
  const int b = bk / K_HEADSC;
  __shared__ __align__(16) ushort_t xv_s[32 * 68];
  __shared__ __align__(16) float pw_s[CHUNK_L];
  const int l0 = chunk * CHUNK_L;
  {
    const int h = t & 31, r0 = t >> 5;
#pragma unroll
    for (int rr = 0; rr < CHUNK_L / 8; rr++) {
      const int l = r0 + rr * 8;
      xv_s[h * 68 + l] = xv[(size_t)(b * L_SEQC + l0 + l) * D_MODELC + k * H_DIMC + h];
    }
  }
  if (t < CHUNK_L)
    pw_s[t] = pw[(size_t)(b * L_SEQC + l0 + t) * K_HEADSC + k];
  const float d0 = dlog[0], d1 = dlog[1], d2 = dlog[2];
  const float mx = fmaxf(d0, fmaxf(d1, d2));
  const float e0 = __expf(d0 - mx), e1 = __expf(d1 - mx), e2 = __expf(d2 - mx);
  const float inv_sum = 1.f / (e0 + e1 + e2);
  const float w0 = e0 * inv_sum, w1 = e1 * inv_sum, w2 = e2 * inv_sum;
  const int c = t & 127;
  const int h = c >> 2;
  const bool is_re = (t < 128);
  const float th = theta[k * 128 + c];
  __syncthreads();
  float acc = 0.f;
  const int xoff = h * 68;
  for (int l4 = 0; l4 < CHUNK_L; l4 += 4) {
    ushort4 xr = *(const ushort4*)(xv_s + xoff + l4);
    float4 pw4 = *(const float4*)(pw_s + l4);
    const float xs[4] = {bf2f(xr.x), bf2f(xr.y), bf2f(xr.z), bf2f(xr.w)};
    const float ps[4] = {pw4.x, pw4.y, pw4.z, pw4.w};
#pragma unroll
    for (int j = 0; j < 4; j++) {
      const float xx = xs[j];
      const float phi = xx * th;
      const float poly = fmaf(-w2 * xx, xx, fmaf(w1, xx, w0));
      const float tr = is_re ? __cosf(phi) : __sinf(phi);
      acc = fmaf(ps[j] * poly, tr, acc);
    }
  }
  const size_t base = (size_t)blockIdx.x * 257;
  cs[base + t] = acc;
  if (t == 0) {
    float s = 0.f;
    for (int l = 0; l < CHUNK_L; l++) s += pw_s[l];
    cs[base + 256] = s;
  }
}

// ---------------------------------------------------------------------------
// scan phase 2: exclusive scan over the NCHUNK chunk-sums per (b,k,channel)
// ---------------------------------------------------------------------------
__global__ __launch_bounds__(256) void scan_chunks(float* __restrict__ cs) {
  const int idx = blockIdx.x * 256 + threadIdx.x;
  if (idx >= B_SZC * K_HEADSC * 257) return;
  const int c = idx % 257;
  const int bk = idx / 257;
  float s = 0.f;
  for (int ch = 0; ch < NCHUNK; ++ch) {
    const size_t p = (size_t)(bk * NCHUNK + ch) * 257 + c;
    const float v = cs[p];
    cs[p] = s;
    s += v;
  }
}

// ---------------------------------------------------------------------------
// scan phase 3 (restructured):
//  A: per-channel cumsum -> v (bf16) into LDS tile [64 l][264 c]
//  B: block sumsq reduction for RMS (all 64 l at once)
//  C: 64x256 @ 256x32 projection via MFMA; rsq+gate in epilogue
// ---------------------------------------------------------------------------
__global__ __launch_bounds__(256) void scan_apply(
    const ushort_t* __restrict__ xv, const float* __restrict__ pw,
    const ushort_t* __restrict__ gate, const float* __restrict__ theta,
    const float* __restrict__ dlog, const float* __restrict__ nsc,
    const float* __restrict__ W_re, const float* __restrict__ W_im,
    const float* __restrict__ cs, ushort_t* __restrict__ ypre) {
  const int t = threadIdx.x;
  const int chunk = blockIdx.x % NCHUNK;
  const int bk = blockIdx.x / NCHUNK;
  const int k = bk % K_HEADSC;
  const int b = bk / K_HEADSC;
  __shared__ __align__(16) ushort_t xv_s[32 * 68];
  __shared__ __align__(16) float pw_s[CHUNK_L];
  __shared__ __align__(16) float inv_s[CHUNK_L];
  __shared__ __align__(16) ushort_t v_s[CHUNK_L * 264];
  __shared__ __align__(16) ushort_t wt_s[32 * 264];
  __shared__ __align__(16) float part_s[256];
  __shared__ __align__(16) float rsq_s[CHUNK_L];

  const int l0 = chunk * CHUNK_L;
  // --- preload xv transposed [h][l] ---
  {
    const int h = t & 31, r0 = t >> 5;
#pragma unroll
    for (int rr = 0; rr < CHUNK_L / 8; rr++) {
      const int l = r0 + rr * 8;
      xv_s[h * 68 + l] = xv[(size_t)(b * L_SEQC + l0 + l) * D_MODELC + k * H_DIMC + h];
    }
  }
  if (t < CHUNK_L)
    pw_s[t] = pw[(size_t)(b * L_SEQC + l0 + t) * K_HEADSC + k];
  // --- preload Wt (W_re/W_im scaled by norm_scale), bf16, [h][264 c] ---
  for (int i = t; i < 32 * 256; i += 256) {
    const int h = i & 31, c = i >> 5;
    const float wv = ((c < 128) ? W_re[c * 32 + h] : W_im[(c - 128) * 32 + h]) * nsc[c];
    wt_s[h * 264 + c] = f2bf(wv);
  }
  const float d0 = dlog[0], d1 = dlog[1], d2 = dlog[2];
  const float mx = fmaxf(d0, fmaxf(d1, d2));
  const float e0 = __expf(d0 - mx), e1 = __expf(d1 - mx), e2 = __expf(d2 - mx);
  const float inv_sum = 1.f / (e0 + e1 + e2);
  const float w0 = e0 * inv_sum, w1 = e1 * inv_sum, w2 = e2 * inv_sum;
  const int c = t & 127;
  const int h = c >> 2;
  const bool is_re = (t < 128);
  const float th = theta[k * 128 + c];
  const size_t base = (size_t)blockIdx.x * 257;
  const float off_c = cs[base + t];
  const float den_off = cs[base + 256];
  __syncthreads();
  // --- inv_den via 64-lane shuffle inclusive scan (wave 0) ---
  if (t < 64) {
    float v = pw_s[t];
#pragma unroll
    for (int off = 1; off < 64; off <<= 1) {
      float o = __shfl_up(v, off, 64);
      if (t >= off) v += o;
    }
    inv_s[t] = 1.f / fmaxf(den_off + v, 1e-4f);
  }
  __syncthreads();
  // --- phase A: barrier-free per-channel cumsum, v -> LDS bf16 ---
  {
    float acc = 0.f;
    const int xoff = h * 68;
    for (int l4 = 0; l4 < CHUNK_L; l4 += 4) {
      ushort4 xr = *(const ushort4*)(xv_s + xoff + l4);
      float4 pw4 = *(const float4*)(pw_s + l4);
      float4 iv4 = *(const float4*)(inv_s + l4);
      const float xs[4] = {bf2f(xr.x), bf2f(xr.y), bf2f(xr.z), bf2f(xr.w)};
      const float ps[4] = {pw4.x, pw4.y, pw4.z, pw4.w};
      const float ivs[4] = {iv4.x, iv4.y, iv4.z, iv4.w};
#pragma unroll
      for (int j = 0; j < 4; j++) {
        const float xx = xs[j];
        const float phi = xx * th;
        const float poly = fmaf(-w2 * xx, xx, fmaf(w1, xx, w0));
        const float tr = is_re ? __cosf(phi) : __sinf(phi);
        acc = fmaf(ps[j] * poly, tr, acc);
        v_s[(l4 + j) * 264 + t] = f2bf((off_c + acc) * ivs[j]);
      }
    }
  }
  __syncthreads();
  // --- phase B: sumsq per l (4 partials per l) ---
  {
    const int l = t >> 2, cg = t & 3;
    const ushort_t* vp = v_s + l * 264 + cg * 64;
    float s = 0.f;
#pragma unroll
    for (int i = 0; i < 64; i += 4) {
      ushort4 a = *(const ushort4*)(vp + i);
      const float f0 = bf2f(a.x), f1 = bf2f(a.y), f2v = bf2f(a.z), f3 = bf2f(a.w);
      s = fmaf(f0, f0, s);
      s = fmaf(f1, f1, s);
      s = fmaf(f2v, f2v, s);
      s = fmaf(f3, f3, s);
    }
    part_s[t] = s;
  }
  __syncthreads();
  if (t < 64) {
    float4 p = *(const float4*)(part_s + t * 4);
    rsq_s[t] = rsqrtf((p.x + p.y + p.z + p.w) * (1.f / 256.f) + 1e-5f);
  }
  __syncthreads();
  // --- phase C: projection via MFMA (each wave: 16 l x 32 h, K=256) ---
  {
    const int wave = t >> 6, lane = t & 63;
    const int quad = lane >> 4, r16 = lane & 15;
    f32x4 acc0 = {}, acc1 = {};
    const int m_row = wave * 16 + r16;
#pragma unroll
    for (int kk = 0; kk < 8; kk++) {
      short8 af = *(const short8*)(v_s + m_row * 264 + kk * 32 + quad * 8);
      short8 b0 = *(const short8*)(wt_s + r16 * 264 + kk * 32 + quad * 8);
      short8 b1 = *(const short8*)(wt_s + (16 + r16) * 264 + kk * 32 + quad * 8);
      acc0 = __builtin_amdgcn_mfma_f32_16x16x32_bf16(af, b0, acc0, 0, 0, 0);
      acc1 = __builtin_amdgcn_mfma_f32_16x16x32_bf16(af, b1, acc1, 0, 0, 0);
    }
#pragma unroll
    for (int r = 0; r < 4; r++) {
      const int l = wave * 16 + quad * 4 + r;
      const float rs = rsq_s[l];
      const size_t row = (size_t)(b * L_SEQC + l0 + l) * D_MODELC + k * H_DIMC;
      const int h0 = r16, h1 = 16 + r16;
      ypre[row + h0] = f2bf(acc0[r] * rs * bf2f(gate[row + h0]));
      ypre[row + h1] = f2bf(acc1[r] * rs * bf2f(gate[row + h1]));
    }
  }
}

// ---------------------------------------------------------------------------
extern "C" void kernel_launch(void* const* d_in, const int* in_sizes, int n_in,
                              void* d_out, int out_size, void* d_ws, size_t ws_size,
                              hipStream_t stream) {
  const float* x       = (const float*)d_in[0];
  const float* W_in    = (const float*)d_in[1];
  const float* w_conv  = (const float*)d_in[2];
  const float* b_conv  = (const float*)d_in[3];
  const float* theta   = (const float*)d_in[4];
  const float* dec     = (const float*)d_in[5];
  const float* anc     = (const float*)d_in[6];
  const float* score   = (const float*)d_in[7];
  const float* dlog    = (const float*)d_in[8];
  const float* nsc     = (const float*)d_in[9];
  const float* W_re    = (const float*)d_in[10];
  const float* W_im    = (const float*)d_in[11];
  const float* W_out   = (const float*)d_in[12];
  float* out = (float*)d_out;

  char* wsb = (char*)d_ws;
  float*    z    = (float*)(wsb + 0);             // 68,157,440 B
  ushort_t* ypre = (ushort_t*)(wsb + 0);          // alias (z dead), 16.8 MB
  ushort_t* WtO  = (ushort_t*)(wsb + 16777216);   // alias in z region
  float*    cs   = (float*)(wsb + 20971520);      // alias in z region, 4.2 MB
  ushort_t* xv   = (ushort_t*)(wsb + 68157440);   // 16,777,216
  ushort_t* gate = (ushort_t*)(wsb + 84934656);   // 16,777,216
  float*    pwb  = (float*)(wsb + 101711872);     // 1,048,576
  ushort_t* xb   = (ushort_t*)(wsb + 102760448);  // 16,777,216
  ushort_t* WtI  = (ushort_t*)(wsb + 119537664);  // 4,456,448
  // total 123,994,112 B

  dim3 blk(256);
  const int M = B_SZC * L_SEQC;  // 8192

  cvt_bf16<<<dim3(M * D_MODELC / 1024), blk, 0, stream>>>(x, xb, M * D_MODELC);
  cvt_t_bf16<<<dim3(2176 / 32, D_MODELC / 32), blk, 0, stream>>>(
      W_in, WtI, D_MODELC, TOTALC, 2176);
  gemm_bf16_bt<<<dim3(2176 / 128, M / 128), blk, 0, stream>>>(
      xb, WtI, z, M, D_MODELC, TOTALC);
  conv_act<<<dim3((B_SZC * L_SEQC * TOTALC) / 256), blk, 0, stream>>>(
      z, w_conv, b_conv, score, dec, anc, xv, gate, pwb);
  // z dead from here; WtO/cs/ypre alias its region
  cvt_t_bf16<<<dim3(D_MODELC / 32, D_MODELC / 32), blk, 0, stream>>>(
      W_out, WtO, D_MODELC, D_MODELC, D_MODELC);
  scan_partial<<<dim3(B_SZC * K_HEADSC * NCHUNK), blk, 0, stream>>>(
      xv, pwb, theta, dlog, cs);
  scan_chunks<<<dim3((B_SZC * K_HEADSC * 257 + 255) / 256), blk, 0, stream>>>(cs);
  scan_apply<<<dim3(B_SZC * K_HEADSC * NCHUNK), blk, 0, stream>>>(
      xv, pwb, gate, theta, dlog, nsc, W_re, W_im, cs, ypre);
  gemm_bf16_bt<<<dim3(D_MODELC / 128, M / 128), blk, 0, stream>>>(
      ypre, WtO, out, M, D_MODELC, D_MODELC);
}

// Round 4
// 332.510 us; speedup vs baseline: 3.8306x; 1.1688x over previous
//
#include <hip/hip_runtime.h>
#include <math.h>

#define D_MODELC 1024
#define K_HEADSC 32
#define ANCHORC 4
#define M_THETAC 4
#define H_DIMC 32
#define TOTALC 2080
#define B_SZC 4
#define L_SEQC 2048
#define NCHUNK 32
#define CHUNK_L (L_SEQC / NCHUNK)  // 64

typedef unsigned short ushort_t;
typedef __attribute__((ext_vector_type(8))) short short8;
typedef __attribute__((ext_vector_type(4))) float f32x4;

__device__ __forceinline__ ushort_t f2bf(float f) {
  union { float f; unsigned u; } v; v.f = f;
  unsigned u = v.u;
  return (ushort_t)((u + 0x7fffu + ((u >> 16) & 1u)) >> 16);
}
__device__ __forceinline__ float bf2f(ushort_t b) {
  union { unsigned u; float f; } v; v.u = ((unsigned)b) << 16;
  return v.f;
}

// ---------------------------------------------------------------------------
// fp32 -> bf16 elementwise (n divisible by 1024)
// ---------------------------------------------------------------------------
__global__ __launch_bounds__(256) void cvt_bf16(
    const float* __restrict__ in, ushort_t* __restrict__ out, int n) {
  const int i = (blockIdx.x * 256 + threadIdx.x) * 4;
  if (i >= n) return;
  float4 v = *(const float4*)(in + i);
  ushort4 o = {f2bf(v.x), f2bf(v.y), f2bf(v.z), f2bf(v.w)};
  *(ushort4*)(out + i) = o;
}

// ---------------------------------------------------------------------------
// fp32 [K,N] -> bf16 transposed [Npad,K], zero-padding rows N..Npad-1
// ---------------------------------------------------------------------------
__global__ __launch_bounds__(256) void cvt_t_bf16(
    const float* __restrict__ W, ushort_t* __restrict__ Wt,
    int K, int N, int Npad) {
  __shared__ float tile[32][33];
  const int n0 = blockIdx.x * 32, k0 = blockIdx.y * 32;
  const int tx = threadIdx.x & 31, ty = threadIdx.x >> 5;
#pragma unroll
  for (int i = 0; i < 4; i++) {
    const int kk = ty + i * 8;
    const int n = n0 + tx;
    tile[kk][tx] = (n < N) ? W[(size_t)(k0 + kk) * N + n] : 0.f;
  }
  __syncthreads();
#pragma unroll
  for (int i = 0; i < 4; i++) {
    const int nn = ty + i * 8;
    Wt[(size_t)(n0 + nn) * K + k0 + tx] = f2bf(tile[tx][nn]);
  }
}

// ---------------------------------------------------------------------------
// pack W_re/W_im * norm_scale into bf16 [32 h][256 c] (B-fragment layout)
// ---------------------------------------------------------------------------
__global__ __launch_bounds__(256) void wt_pack(
    const float* __restrict__ W_re, const float* __restrict__ W_im,
    const float* __restrict__ nsc, ushort_t* __restrict__ wtp) {
  const int i = blockIdx.x * 256 + threadIdx.x;
  if (i >= 32 * 256) return;
  const int h = i & 31, c = i >> 5;
  const float wv = ((c < 128) ? W_re[c * 32 + h] : W_im[(c - 128) * 32 + h]) * nsc[c];
  wtp[h * 256 + c] = f2bf(wv);
}

// ---------------------------------------------------------------------------
// bf16 MFMA GEMM: C[M,Nout] = A[M,K] @ Bt[N,K]^T  (out fp32 or bf16)
// ---------------------------------------------------------------------------
template <bool OBF16>
__global__ __launch_bounds__(256) void gemm_bf16_bt(
    const ushort_t* __restrict__ A, const ushort_t* __restrict__ Bt,
    void* __restrict__ Cv, int M, int K, int Nout) {
  __shared__ ushort_t As[128 * 32];
  __shared__ ushort_t Bs[128 * 32];
  const int t = threadIdx.x;
  const int wave = t >> 6, lane = t & 63;
  const int m0 = blockIdx.y * 128, n0 = blockIdx.x * 128;
  const int m0w = (wave >> 1) * 64, n0w = (wave & 1) * 64;
  const int quad = lane >> 4, r16 = lane & 15;

  f32x4 acc[4][4] = {};

  for (int k0 = 0; k0 < K; k0 += 32) {
    __syncthreads();
#pragma unroll
    for (int i = 0; i < 2; i++) {
      const int seg = wave * 2 + i;
      const int byteoff = seg * 1024 + lane * 16;
      const int row = byteoff >> 6;
      const int col = (byteoff & 63) >> 1;
      const ushort_t* gpA = A + (size_t)(m0 + row) * K + k0 + col;
      const ushort_t* gpB = Bt + (size_t)(n0 + row) * K + k0 + col;
      __builtin_amdgcn_global_load_lds(
          (const __attribute__((address_space(1))) void*)gpA,
          (__attribute__((address_space(3))) void*)(As + seg * 512), 16, 0, 0);
      __builtin_amdgcn_global_load_lds(
          (const __attribute__((address_space(1))) void*)gpB,
          (__attribute__((address_space(3))) void*)(Bs + seg * 512), 16, 0, 0);
    }
    __syncthreads();
    short8 af[4], bfv[4];
#pragma unroll
    for (int i = 0; i < 4; i++)
      af[i] = *(const short8*)(As + (m0w + i * 16 + r16) * 32 + quad * 8);
#pragma unroll
    for (int j = 0; j < 4; j++)
      bfv[j] = *(const short8*)(Bs + (n0w + j * 16 + r16) * 32 + quad * 8);
#pragma unroll
    for (int i = 0; i < 4; i++)
#pragma unroll
      for (int j = 0; j < 4; j++)
        acc[i][j] = __builtin_amdgcn_mfma_f32_16x16x32_bf16(
            af[i], bfv[j], acc[i][j], 0, 0, 0);
  }

#pragma unroll
  for (int i = 0; i < 4; i++) {
#pragma unroll
    for (int j = 0; j < 4; j++) {
      const int n = n0 + n0w + j * 16 + r16;
      if (n >= Nout) continue;
#pragma unroll
      for (int r = 0; r < 4; r++) {
        const int m = m0 + m0w + i * 16 + quad * 4 + r;
        if constexpr (OBF16) {
          ((ushort_t*)Cv)[(size_t)m * Nout + n] = f2bf(acc[i][j][r]);
        } else {
          ((float*)Cv)[(size_t)m * Nout + n] = acc[i][j][r];
        }
      }
    }
  }
}

// ---------------------------------------------------------------------------
// conv (causal depthwise k=4) on bf16 z, x4 vectorized; outputs xv/gate/pw
// ---------------------------------------------------------------------------
__global__ __launch_bounds__(256) void conv_act(
    const ushort_t* __restrict__ z, const float* __restrict__ wconv,
    const float* __restrict__ bconv, const float* __restrict__ score_scale,
    const float* __restrict__ dec_slopes, const float* __restrict__ anc_slopes,
    ushort_t* __restrict__ xv, ushort_t* __restrict__ gate,
    float* __restrict__ pw) {
  const int idx = blockIdx.x * 256 + threadIdx.x;
  if (idx >= B_SZC * L_SEQC * (TOTALC / 4)) return;
  const int c4 = (idx % (TOTALC / 4)) * 4;
  const int bl = idx / (TOTALC / 4);
  const int l = bl % L_SEQC;
  float4 bc = *(const float4*)(bconv + c4);
  float acc[4] = {bc.x, bc.y, bc.z, bc.w};
#pragma unroll
  for (int j = 0; j < 4; j++) {
    const int ls = l - 3 + j;
    if (ls >= 0) {
      ushort4 zr = *(const ushort4*)(z + (size_t)(bl - l + ls) * TOTALC + c4);
      float4 wc = *(const float4*)(wconv + j * TOTALC + c4);
      acc[0] = fmaf(bf2f(zr.x), wc.x, acc[0]);
      acc[1] = fmaf(bf2f(zr.y), wc.y, acc[1]);
      acc[2] = fmaf(bf2f(zr.z), wc.z, acc[2]);
      acc[3] = fmaf(bf2f(zr.w), wc.w, acc[3]);
    }
  }
  if (c4 < D_MODELC) {
    ushort4 o = {f2bf(acc[0]), f2bf(acc[1]), f2bf(acc[2]), f2bf(acc[3])};
    *(ushort4*)(xv + (size_t)bl * D_MODELC + c4) = o;
  } else if (c4 < 2 * D_MODELC) {
    ushort4 o;
    o.x = f2bf(acc[0] / (1.f + __expf(-acc[0])));
    o.y = f2bf(acc[1] / (1.f + __expf(-acc[1])));
    o.z = f2bf(acc[2] / (1.f + __expf(-acc[2])));
    o.w = f2bf(acc[3] / (1.f + __expf(-acc[3])));
    *(ushort4*)(gate + (size_t)bl * D_MODELC + (c4 - D_MODELC)) = o;
  } else {
    const int k0 = c4 - 2 * D_MODELC;  // 0,4,...,28 (group-uniform regime)
    float4 o;
    float* op = &o.x;
#pragma unroll
    for (int i = 0; i < 4; i++) {
      const int k = k0 + i;
      float sv = fminf(fmaxf(score_scale[k] * acc[i], -20.f), 20.f);
      float p = __expf(sv);
      float tw;
      if (k0 < K_HEADSC - ANCHORC) {
        float sd = log1pf(__expf(dec_slopes[k]));
        tw = __expf(-sd * (float)(L_SEQC - 1 - l));
      } else {
        float sa = log1pf(__expf(anc_slopes[k - (K_HEADSC - ANCHORC)]));
        tw = __expf(-sa * (float)l);
      }
      op[i] = p * tw;
    }
    *(float4*)(pw + (size_t)bl * K_HEADSC + k0) = o;
  }
}

// ---------------------------------------------------------------------------
// scan phase 1: per (b,k,chunk) sums of pw*poly*cos/sin (257 channels)
// ---------------------------------------------------------------------------
__global__ __launch_bounds__(256) void scan_partial(
    const ushort_t* __restrict__ xv, const float* __restrict__ pw,
    const float* __restrict__ theta, const float* __restrict__ dlog,
    float* __restrict__ cs) {
  const int t = threadIdx.x;
  const int chunk = blockIdx.x % NCHUNK;
  const int bk = blockIdx.x / NCHUNK;
  const int k = bk % K_HEADSC;
  const int b = bk / K_HEADSC;
  __shared__ __align__(16) ushort_t xv_s[32 * 68];
  __shared__ __align__(16) float pw_s[CHUNK_L];
  const int l0 = chunk * CHUNK_L;
  {
    const int h = t & 31, r0 = t >> 5;
#pragma unroll
    for (int rr = 0; rr < CHUNK_L / 8; rr++) {
      const int l = r0 + rr * 8;
      xv_s[h * 68 + l] = xv[(size_t)(b * L_SEQC + l0 + l) * D_MODELC + k * H_DIMC + h];
    }
  }
  if (t < CHUNK_L)
    pw_s[t] = pw[(size_t)(b * L_SEQC + l0 + t) * K_HEADSC + k];
  const float d0 = dlog[0], d1 = dlog[1], d2 = dlog[2];
  const float mx = fmaxf(d0, fmaxf(d1, d2));
  const float e0 = __expf(d0 - mx), e1 = __expf(d1 - mx), e2 = __expf(d2 - mx);
  const float inv_sum = 1.f / (e0 + e1 + e2);
  const float w0 = e0 * inv_sum, w1 = e1 * inv_sum, w2 = e2 * inv_sum;
  const int c = t & 127;
  const int h = c >> 2;
  const bool is_re = (t < 128);
  const float th = theta[k * 128 + c];
  __syncthreads();
  float acc = 0.f;
  const int xoff = h * 68;
  for (int l4 = 0; l4 < CHUNK_L; l4 += 4) {
    ushort4 xr = *(const ushort4*)(xv_s + xoff + l4);
    float4 pw4 = *(const float4*)(pw_s + l4);
    const float xs[4] = {bf2f(xr.x), bf2f(xr.y), bf2f(xr.z), bf2f(xr.w)};
    const float ps[4] = {pw4.x, pw4.y, pw4.z, pw4.w};
#pragma unroll
    for (int j = 0; j < 4; j++) {
      const float xx = xs[j];
      const float phi = xx * th;
      const float poly = fmaf(-w2 * xx, xx, fmaf(w1, xx, w0));
      const float tr = is_re ? __cosf(phi) : __sinf(phi);
      acc = fmaf(ps[j] * poly, tr, acc);
    }
  }
  const size_t base = (size_t)blockIdx.x * 257;
  cs[base + t] = acc;
  if (t == 0) {
    float s = 0.f;
    for (int l = 0; l < CHUNK_L; l++) s += pw_s[l];
    cs[base + 256] = s;
  }
}

// ---------------------------------------------------------------------------
// scan phase 2: exclusive scan over the NCHUNK chunk-sums per (b,k,channel)
// ---------------------------------------------------------------------------
__global__ __launch_bounds__(256) void scan_chunks(float* __restrict__ cs) {
  const int idx = blockIdx.x * 256 + threadIdx.x;
  if (idx >= B_SZC * K_HEADSC * 257) return;
  const int c = idx % 257;
  const int bk = idx / 257;
  float s = 0.f;
  for (int ch = 0; ch < NCHUNK; ++ch) {
    const size_t p = (size_t)(bk * NCHUNK + ch) * 257 + c;
    const float v = cs[p];
    cs[p] = s;
    s += v;
  }
}

// ---------------------------------------------------------------------------
// scan phase 3:
//  A: per-channel cumsum -> v (bf16) into LDS [64 l][264 c]
//  B: block sumsq for RMS
//  C: 64x256 @ 256x32 projection via MFMA (W frags from packed global table)
// ---------------------------------------------------------------------------
__global__ __launch_bounds__(256, 4) void scan_apply(
    const ushort_t* __restrict__ xv, const float* __restrict__ pw,
    const ushort_t* __restrict__ gate, const float* __restrict__ theta,
    const float* __restrict__ dlog, const ushort_t* __restrict__ wtp,
    const float* __restrict__ cs, ushort_t* __restrict__ ypre) {
  const int t = threadIdx.x;
  const int chunk = blockIdx.x % NCHUNK;
  const int bk = blockIdx.x / NCHUNK;
  const int k = bk % K_HEADSC;
  const int b = bk / K_HEADSC;
  __shared__ __align__(16) ushort_t xv_s[32 * 68];
  __shared__ __align__(16) float pw_s[CHUNK_L];
  __shared__ __align__(16) float inv_s[CHUNK_L];
  __shared__ __align__(16) ushort_t v_s[CHUNK_L * 264];
  __shared__ __align__(16) float part_s[256];
  __shared__ __align__(16) float rsq_s[CHUNK_L];

  const int l0 = chunk * CHUNK_L;
  {
    const int h = t & 31, r0 = t >> 5;
#pragma unroll
    for (int rr = 0; rr < CHUNK_L / 8; rr++) {
      const int l = r0 + rr * 8;
      xv_s[h * 68 + l] = xv[(size_t)(b * L_SEQC + l0 + l) * D_MODELC + k * H_DIMC + h];
    }
  }
  if (t < CHUNK_L)
    pw_s[t] = pw[(size_t)(b * L_SEQC + l0 + t) * K_HEADSC + k];
  const float d0 = dlog[0], d1 = dlog[1], d2 = dlog[2];
  const float mx = fmaxf(d0, fmaxf(d1, d2));
  const float e0 = __expf(d0 - mx), e1 = __expf(d1 - mx), e2 = __expf(d2 - mx);
  const float inv_sum = 1.f / (e0 + e1 + e2);
  const float w0 = e0 * inv_sum, w1 = e1 * inv_sum, w2 = e2 * inv_sum;
  const int c = t & 127;
  const int h = c >> 2;
  const bool is_re = (t < 128);
  const float th = theta[k * 128 + c];
  const size_t base = (size_t)blockIdx.x * 257;
  const float off_c = cs[base + t];
  const float den_off = cs[base + 256];
  __syncthreads();
  if (t < 64) {
    float v = pw_s[t];
#pragma unroll
    for (int off = 1; off < 64; off <<= 1) {
      float o = __shfl_up(v, off, 64);
      if (t >= off) v += o;
    }
    inv_s[t] = 1.f / fmaxf(den_off + v, 1e-4f);
  }
  __syncthreads();
  // --- phase A ---
  {
    float acc = 0.f;
    const int xoff = h * 68;
    for (int l4 = 0; l4 < CHUNK_L; l4 += 4) {
      ushort4 xr = *(const ushort4*)(xv_s + xoff + l4);
      float4 pw4 = *(const float4*)(pw_s + l4);
      float4 iv4 = *(const float4*)(inv_s + l4);
      const float xs[4] = {bf2f(xr.x), bf2f(xr.y), bf2f(xr.z), bf2f(xr.w)};
      const float ps[4] = {pw4.x, pw4.y, pw4.z, pw4.w};
      const float ivs[4] = {iv4.x, iv4.y, iv4.z, iv4.w};
#pragma unroll
      for (int j = 0; j < 4; j++) {
        const float xx = xs[j];
        const float phi = xx * th;
        const float poly = fmaf(-w2 * xx, xx, fmaf(w1, xx, w0));
        const float tr = is_re ? __cosf(phi) : __sinf(phi);
        acc = fmaf(ps[j] * poly, tr, acc);
        v_s[(l4 + j) * 264 + t] = f2bf((off_c + acc) * ivs[j]);
      }
    }
  }
  __syncthreads();
  // --- phase B ---
  {
    const int l = t >> 2, cg = t & 3;
    const ushort_t* vp = v_s + l * 264 + cg * 64;
    float s = 0.f;
#pragma unroll
    for (int i = 0; i < 64; i += 4) {
      ushort4 a = *(const ushort4*)(vp + i);
      const float f0 = bf2f(a.x), f1 = bf2f(a.y), f2v = bf2f(a.z), f3 = bf2f(a.w);
      s = fmaf(f0, f0, s);
      s = fmaf(f1, f1, s);
      s = fmaf(f2v, f2v, s);
      s = fmaf(f3, f3, s);
    }
    part_s[t] = s;
  }
  __syncthreads();
  if (t < 64) {
    float4 p = *(const float4*)(part_s + t * 4);
    rsq_s[t] = rsqrtf((p.x + p.y + p.z + p.w) * (1.f / 256.f) + 1e-5f);
  }
  __syncthreads();
  // --- phase C ---
  {
    const int wave = t >> 6, lane = t & 63;
    const int quad = lane >> 4, r16 = lane & 15;
    f32x4 acc0 = {}, acc1 = {};
    const int m_row = wave * 16 + r16;
    const ushort_t* wb0 = wtp + r16 * 256;
    const ushort_t* wb1 = wtp + (16 + r16) * 256;
#pragma unroll
    for (int kk = 0; kk < 8; kk++) {
      short8 af = *(const short8*)(v_s + m_row * 264 + kk * 32 + quad * 8);
      short8 b0 = *(const short8*)(wb0 + kk * 32 + quad * 8);
      short8 b1 = *(const short8*)(wb1 + kk * 32 + quad * 8);
      acc0 = __builtin_amdgcn_mfma_f32_16x16x32_bf16(af, b0, acc0, 0, 0, 0);
      acc1 = __builtin_amdgcn_mfma_f32_16x16x32_bf16(af, b1, acc1, 0, 0, 0);
    }
#pragma unroll
    for (int r = 0; r < 4; r++) {
      const int l = wave * 16 + quad * 4 + r;
      const float rs = rsq_s[l];
      const size_t row = (size_t)(b * L_SEQC + l0 + l) * D_MODELC + k * H_DIMC;
      const int h0 = r16, h1 = 16 + r16;
      ypre[row + h0] = f2bf(acc0[r] * rs * bf2f(gate[row + h0]));
      ypre[row + h1] = f2bf(acc1[r] * rs * bf2f(gate[row + h1]));
    }
  }
}

// ---------------------------------------------------------------------------
extern "C" void kernel_launch(void* const* d_in, const int* in_sizes, int n_in,
                              void* d_out, int out_size, void* d_ws, size_t ws_size,
                              hipStream_t stream) {
  const float* x       = (const float*)d_in[0];
  const float* W_in    = (const float*)d_in[1];
  const float* w_conv  = (const float*)d_in[2];
  const float* b_conv  = (const float*)d_in[3];
  const float* theta   = (const float*)d_in[4];
  const float* dec     = (const float*)d_in[5];
  const float* anc     = (const float*)d_in[6];
  const float* score   = (const float*)d_in[7];
  const float* dlog    = (const float*)d_in[8];
  const float* nsc     = (const float*)d_in[9];
  const float* W_re    = (const float*)d_in[10];
  const float* W_im    = (const float*)d_in[11];
  const float* W_out   = (const float*)d_in[12];
  float* out = (float*)d_out;

  char* wsb = (char*)d_ws;
  ushort_t* z    = (ushort_t*)(wsb + 0);          // bf16, 34,078,720 B
  ushort_t* ypre = (ushort_t*)(wsb + 0);          // alias (z dead), 16.8 MB
  ushort_t* WtO  = (ushort_t*)(wsb + 16777216);   // alias, 2 MB
  float*    cs   = (float*)(wsb + 20971520);      // alias, 4.2 MB
  ushort_t* wtp  = (ushort_t*)(wsb + 26214400);   // alias, 16 KB
  ushort_t* xv   = (ushort_t*)(wsb + 68157440);   // 16,777,216
  ushort_t* gate = (ushort_t*)(wsb + 84934656);   // 16,777,216
  float*    pwb  = (float*)(wsb + 101711872);     // 1,048,576
  ushort_t* xb   = (ushort_t*)(wsb + 102760448);  // 16,777,216
  ushort_t* WtI  = (ushort_t*)(wsb + 119537664);  // 4,456,448
  // total 123,994,112 B

  dim3 blk(256);
  const int M = B_SZC * L_SEQC;  // 8192

  cvt_bf16<<<dim3(M * D_MODELC / 1024), blk, 0, stream>>>(x, xb, M * D_MODELC);
  cvt_t_bf16<<<dim3(2176 / 32, D_MODELC / 32), blk, 0, stream>>>(
      W_in, WtI, D_MODELC, TOTALC, 2176);
  gemm_bf16_bt<true><<<dim3(2176 / 128, M / 128), blk, 0, stream>>>(
      xb, WtI, z, M, D_MODELC, TOTALC);
  conv_act<<<dim3((B_SZC * L_SEQC * (TOTALC / 4) + 255) / 256), blk, 0, stream>>>(
      z, w_conv, b_conv, score, dec, anc, xv, gate, pwb);
  // z dead from here; WtO/cs/wtp/ypre alias its region
  cvt_t_bf16<<<dim3(D_MODELC / 32, D_MODELC / 32), blk, 0, stream>>>(
      W_out, WtO, D_MODELC, D_MODELC, D_MODELC);
  wt_pack<<<dim3(32), blk, 0, stream>>>(W_re, W_im, nsc, wtp);
  scan_partial<<<dim3(B_SZC * K_HEADSC * NCHUNK), blk, 0, stream>>>(
      xv, pwb, theta, dlog, cs);
  scan_chunks<<<dim3((B_SZC * K_HEADSC * 257 + 255) / 256), blk, 0, stream>>>(cs);
  scan_apply<<<dim3(B_SZC * K_HEADSC * NCHUNK), blk, 0, stream>>>(
      xv, pwb, gate, theta, dlog, wtp, cs, ypre);
  gemm_bf16_bt<false><<<dim3(D_MODELC / 128, M / 128), blk, 0, stream>>>(
      ypre, WtO, out, M, D_MODELC, D_MODELC);
}

// Round 5
// 324.508 us; speedup vs baseline: 3.9251x; 1.0247x over previous
//
#include <hip/hip_runtime.h>
#include <math.h>

#define D_MODELC 1024
#define K_HEADSC 32
#define ANCHORC 4
#define M_THETAC 4
#define H_DIMC 32
#define TOTALC 2080
#define B_SZC 4
#define L_SEQC 2048
#define NCHUNK 32
#define CHUNK_L (L_SEQC / NCHUNK)  // 64

typedef unsigned short ushort_t;
typedef __attribute__((ext_vector_type(8))) short short8;
typedef __attribute__((ext_vector_type(4))) float f32x4;

__device__ __forceinline__ ushort_t f2bf(float f) {
  union { float f; unsigned u; } v; v.f = f;
  unsigned u = v.u;
  return (ushort_t)((u + 0x7fffu + ((u >> 16) & 1u)) >> 16);
}
__device__ __forceinline__ float bf2f(ushort_t b) {
  union { unsigned u; float f; } v; v.u = ((unsigned)b) << 16;
  return v.f;
}

// ---------------------------------------------------------------------------
// fp32 -> bf16 elementwise (n divisible by 1024)
// ---------------------------------------------------------------------------
__global__ __launch_bounds__(256) void cvt_bf16(
    const float* __restrict__ in, ushort_t* __restrict__ out, int n) {
  const int i = (blockIdx.x * 256 + threadIdx.x) * 4;
  if (i >= n) return;
  float4 v = *(const float4*)(in + i);
  ushort4 o = {f2bf(v.x), f2bf(v.y), f2bf(v.z), f2bf(v.w)};
  *(ushort4*)(out + i) = o;
}

// ---------------------------------------------------------------------------
// fp32 [K,N] -> bf16 transposed [Npad,K], zero-padding rows N..Npad-1
// ---------------------------------------------------------------------------
__global__ __launch_bounds__(256) void cvt_t_bf16(
    const float* __restrict__ W, ushort_t* __restrict__ Wt,
    int K, int N, int Npad) {
  __shared__ float tile[32][33];
  const int n0 = blockIdx.x * 32, k0 = blockIdx.y * 32;
  const int tx = threadIdx.x & 31, ty = threadIdx.x >> 5;
#pragma unroll
  for (int i = 0; i < 4; i++) {
    const int kk = ty + i * 8;
    const int n = n0 + tx;
    tile[kk][tx] = (n < N) ? W[(size_t)(k0 + kk) * N + n] : 0.f;
  }
  __syncthreads();
#pragma unroll
  for (int i = 0; i < 4; i++) {
    const int nn = ty + i * 8;
    Wt[(size_t)(n0 + nn) * K + k0 + tx] = f2bf(tile[tx][nn]);
  }
}

// ---------------------------------------------------------------------------
// pack W_re/W_im * norm_scale into bf16 [32 h][256 c] (B-fragment layout)
// ---------------------------------------------------------------------------
__global__ __launch_bounds__(256) void wt_pack(
    const float* __restrict__ W_re, const float* __restrict__ W_im,
    const float* __restrict__ nsc, ushort_t* __restrict__ wtp) {
  const int i = blockIdx.x * 256 + threadIdx.x;
  if (i >= 32 * 256) return;
  const int h = i & 31, c = i >> 5;
  const float wv = ((c < 128) ? W_re[c * 32 + h] : W_im[(c - 128) * 32 + h]) * nsc[c];
  wtp[h * 256 + c] = f2bf(wv);
}

// ---------------------------------------------------------------------------
// bf16 MFMA GEMM: C[M,Nout] = A[M,K] @ Bt[N,K]^T  (out fp32 or bf16)
// 1D grid with XCD band swizzle: 8 consecutive block ids = 8 rows of one
// column tile -> each XCD keeps a fixed A-row-tile L2-resident for a whole
// band while B-tiles are L3-broadcast across XCDs.
// ---------------------------------------------------------------------------
template <bool OBF16>
__global__ __launch_bounds__(256) void gemm_bf16_bt(
    const ushort_t* __restrict__ A, const ushort_t* __restrict__ Bt,
    void* __restrict__ Cv, int M, int K, int Nout, int GXt) {
  __shared__ ushort_t As[128 * 32];
  __shared__ ushort_t Bs[128 * 32];
  const int t = threadIdx.x;
  const int wave = t >> 6, lane = t & 63;
  // --- band swizzle ---
  const int p = blockIdx.x;
  const int band_sz = GXt * 8;
  const int band = p / band_sz;
  const int q = p % band_sz;
  const int bx = q >> 3;
  const int by = band * 8 + (q & 7);
  const int m0 = by * 128, n0 = bx * 128;
  const int m0w = (wave >> 1) * 64, n0w = (wave & 1) * 64;
  const int quad = lane >> 4, r16 = lane & 15;

  f32x4 acc[4][4] = {};

  for (int k0 = 0; k0 < K; k0 += 32) {
    __syncthreads();
#pragma unroll
    for (int i = 0; i < 2; i++) {
      const int seg = wave * 2 + i;
      const int byteoff = seg * 1024 + lane * 16;
      const int row = byteoff >> 6;
      const int col = (byteoff & 63) >> 1;
      const ushort_t* gpA = A + (size_t)(m0 + row) * K + k0 + col;
      const ushort_t* gpB = Bt + (size_t)(n0 + row) * K + k0 + col;
      __builtin_amdgcn_global_load_lds(
          (const __attribute__((address_space(1))) void*)gpA,
          (__attribute__((address_space(3))) void*)(As + seg * 512), 16, 0, 0);
      __builtin_amdgcn_global_load_lds(
          (const __attribute__((address_space(1))) void*)gpB,
          (__attribute__((address_space(3))) void*)(Bs + seg * 512), 16, 0, 0);
    }
    __syncthreads();
    short8 af[4], bfv[4];
#pragma unroll
    for (int i = 0; i < 4; i++)
      af[i] = *(const short8*)(As + (m0w + i * 16 + r16) * 32 + quad * 8);
#pragma unroll
    for (int j = 0; j < 4; j++)
      bfv[j] = *(const short8*)(Bs + (n0w + j * 16 + r16) * 32 + quad * 8);
#pragma unroll
    for (int i = 0; i < 4; i++)
#pragma unroll
      for (int j = 0; j < 4; j++)
        acc[i][j] = __builtin_amdgcn_mfma_f32_16x16x32_bf16(
            af[i], bfv[j], acc[i][j], 0, 0, 0);
  }

#pragma unroll
  for (int i = 0; i < 4; i++) {
#pragma unroll
    for (int j = 0; j < 4; j++) {
      const int n = n0 + n0w + j * 16 + r16;
      if (n >= Nout) continue;
#pragma unroll
      for (int r = 0; r < 4; r++) {
        const int m = m0 + m0w + i * 16 + quad * 4 + r;
        if constexpr (OBF16) {
          ((ushort_t*)Cv)[(size_t)m * Nout + n] = f2bf(acc[i][j][r]);
        } else {
          ((float*)Cv)[(size_t)m * Nout + n] = acc[i][j][r];
        }
      }
    }
  }
}

// ---------------------------------------------------------------------------
// conv (causal depthwise k=4) on bf16 z, x4 vectorized; outputs xv/gate/pw
// ---------------------------------------------------------------------------
__global__ __launch_bounds__(256) void conv_act(
    const ushort_t* __restrict__ z, const float* __restrict__ wconv,
    const float* __restrict__ bconv, const float* __restrict__ score_scale,
    const float* __restrict__ dec_slopes, const float* __restrict__ anc_slopes,
    ushort_t* __restrict__ xv, ushort_t* __restrict__ gate,
    float* __restrict__ pw) {
  const int idx = blockIdx.x * 256 + threadIdx.x;
  if (idx >= B_SZC * L_SEQC * (TOTALC / 4)) return;
  const int c4 = (idx % (TOTALC / 4)) * 4;
  const int bl = idx / (TOTALC / 4);
  const int l = bl % L_SEQC;
  float4 bc = *(const float4*)(bconv + c4);
  float acc[4] = {bc.x, bc.y, bc.z, bc.w};
#pragma unroll
  for (int j = 0; j < 4; j++) {
    const int ls = l - 3 + j;
    if (ls >= 0) {
      ushort4 zr = *(const ushort4*)(z + (size_t)(bl - l + ls) * TOTALC + c4);
      float4 wc = *(const float4*)(wconv + j * TOTALC + c4);
      acc[0] = fmaf(bf2f(zr.x), wc.x, acc[0]);
      acc[1] = fmaf(bf2f(zr.y), wc.y, acc[1]);
      acc[2] = fmaf(bf2f(zr.z), wc.z, acc[2]);
      acc[3] = fmaf(bf2f(zr.w), wc.w, acc[3]);
    }
  }
  if (c4 < D_MODELC) {
    ushort4 o = {f2bf(acc[0]), f2bf(acc[1]), f2bf(acc[2]), f2bf(acc[3])};
    *(ushort4*)(xv + (size_t)bl * D_MODELC + c4) = o;
  } else if (c4 < 2 * D_MODELC) {
    ushort4 o;
    o.x = f2bf(acc[0] / (1.f + __expf(-acc[0])));
    o.y = f2bf(acc[1] / (1.f + __expf(-acc[1])));
    o.z = f2bf(acc[2] / (1.f + __expf(-acc[2])));
    o.w = f2bf(acc[3] / (1.f + __expf(-acc[3])));
    *(ushort4*)(gate + (size_t)bl * D_MODELC + (c4 - D_MODELC)) = o;
  } else {
    const int k0 = c4 - 2 * D_MODELC;  // 0,4,...,28 (group-uniform regime)
    float4 o;
    float* op = &o.x;
#pragma unroll
    for (int i = 0; i < 4; i++) {
      const int k = k0 + i;
      float sv = fminf(fmaxf(score_scale[k] * acc[i], -20.f), 20.f);
      float p = __expf(sv);
      float tw;
      if (k0 < K_HEADSC - ANCHORC) {
        float sd = log1pf(__expf(dec_slopes[k]));
        tw = __expf(-sd * (float)(L_SEQC - 1 - l));
      } else {
        float sa = log1pf(__expf(anc_slopes[k - (K_HEADSC - ANCHORC)]));
        tw = __expf(-sa * (float)l);
      }
      op[i] = p * tw;
    }
    *(float4*)(pw + (size_t)bl * K_HEADSC + k0) = o;
  }
}

// ---------------------------------------------------------------------------
// scan phase 1: per (b,k,chunk) sums of pw*poly*cos/sin (257 channels)
// ---------------------------------------------------------------------------
__global__ __launch_bounds__(256) void scan_partial(
    const ushort_t* __restrict__ xv, const float* __restrict__ pw,
    const float* __restrict__ theta, const float* __restrict__ dlog,
    float* __restrict__ cs) {
  const int t = threadIdx.x;
  const int chunk = blockIdx.x % NCHUNK;
  const int bk = blockIdx.x / NCHUNK;
  const int k = bk % K_HEADSC;
  const int b = bk / K_HEADSC;
  __shared__ __align__(16) ushort_t xv_s[32 * 68];
  __shared__ __align__(16) float pw_s[CHUNK_L];
  const int l0 = chunk * CHUNK_L;
  {
    const int h = t & 31, r0 = t >> 5;
#pragma unroll
    for (int rr = 0; rr < CHUNK_L / 8; rr++) {
      const int l = r0 + rr * 8;
      xv_s[h * 68 + l] = xv[(size_t)(b * L_SEQC + l0 + l) * D_MODELC + k * H_DIMC + h];
    }
  }
  if (t < CHUNK_L)
    pw_s[t] = pw[(size_t)(b * L_SEQC + l0 + t) * K_HEADSC + k];
  const float d0 = dlog[0], d1 = dlog[1], d2 = dlog[2];
  const float mx = fmaxf(d0, fmaxf(d1, d2));
  const float e0 = __expf(d0 - mx), e1 = __expf(d1 - mx), e2 = __expf(d2 - mx);
  const float inv_sum = 1.f / (e0 + e1 + e2);
  const float w0 = e0 * inv_sum, w1 = e1 * inv_sum, w2 = e2 * inv_sum;
  const int c = t & 127;
  const int h = c >> 2;
  const bool is_re = (t < 128);
  const float th = theta[k * 128 + c];
  __syncthreads();
  float acc = 0.f;
  const int xoff = h * 68;
  for (int l4 = 0; l4 < CHUNK_L; l4 += 4) {
    ushort4 xr = *(const ushort4*)(xv_s + xoff + l4);
    float4 pw4 = *(const float4*)(pw_s + l4);
    const float xs[4] = {bf2f(xr.x), bf2f(xr.y), bf2f(xr.z), bf2f(xr.w)};
    const float ps[4] = {pw4.x, pw4.y, pw4.z, pw4.w};
#pragma unroll
    for (int j = 0; j < 4; j++) {
      const float xx = xs[j];
      const float phi = xx * th;
      const float poly = fmaf(-w2 * xx, xx, fmaf(w1, xx, w0));
      const float tr = is_re ? __cosf(phi) : __sinf(phi);
      acc = fmaf(ps[j] * poly, tr, acc);
    }
  }
  const size_t base = (size_t)blockIdx.x * 257;
  cs[base + t] = acc;
  if (t == 0) {
    float s = 0.f;
    for (int l = 0; l < CHUNK_L; l++) s += pw_s[l];
    cs[base + 256] = s;
  }
}

// ---------------------------------------------------------------------------
// scan phase 2: exclusive scan over the NCHUNK chunk-sums per (b,k,channel)
// ---------------------------------------------------------------------------
__global__ __launch_bounds__(256) void scan_chunks(float* __restrict__ cs) {
  const int idx = blockIdx.x * 256 + threadIdx.x;
  if (idx >= B_SZC * K_HEADSC * 257) return;
  const int c = idx % 257;
  const int bk = idx / 257;
  float s = 0.f;
  for (int ch = 0; ch < NCHUNK; ++ch) {
    const size_t p = (size_t)(bk * NCHUNK + ch) * 257 + c;
    const float v = cs[p];
    cs[p] = s;
    s += v;
  }
}

// ---------------------------------------------------------------------------
// scan phase 3:
//  A: per-channel cumsum -> v (bf16) into LDS [64 l][264 c]
//  B: block sumsq for RMS
//  C: 64x256 @ 256x32 projection via MFMA (W frags from packed global table)
// ---------------------------------------------------------------------------
__global__ __launch_bounds__(256, 4) void scan_apply(
    const ushort_t* __restrict__ xv, const float* __restrict__ pw,
    const ushort_t* __restrict__ gate, const float* __restrict__ theta,
    const float* __restrict__ dlog, const ushort_t* __restrict__ wtp,
    const float* __restrict__ cs, ushort_t* __restrict__ ypre) {
  const int t = threadIdx.x;
  const int chunk = blockIdx.x % NCHUNK;
  const int bk = blockIdx.x / NCHUNK;
  const int k = bk % K_HEADSC;
  const int b = bk / K_HEADSC;
  __shared__ __align__(16) ushort_t xv_s[32 * 68];
  __shared__ __align__(16) float pw_s[CHUNK_L];
  __shared__ __align__(16) float inv_s[CHUNK_L];
  __shared__ __align__(16) ushort_t v_s[CHUNK_L * 264];
  __shared__ __align__(16) float part_s[256];
  __shared__ __align__(16) float rsq_s[CHUNK_L];

  const int l0 = chunk * CHUNK_L;
  {
    const int h = t & 31, r0 = t >> 5;
#pragma unroll
    for (int rr = 0; rr < CHUNK_L / 8; rr++) {
      const int l = r0 + rr * 8;
      xv_s[h * 68 + l] = xv[(size_t)(b * L_SEQC + l0 + l) * D_MODELC + k * H_DIMC + h];
    }
  }
  if (t < CHUNK_L)
    pw_s[t] = pw[(size_t)(b * L_SEQC + l0 + t) * K_HEADSC + k];
  const float d0 = dlog[0], d1 = dlog[1], d2 = dlog[2];
  const float mx = fmaxf(d0, fmaxf(d1, d2));
  const float e0 = __expf(d0 - mx), e1 = __expf(d1 - mx), e2 = __expf(d2 - mx);
  const float inv_sum = 1.f / (e0 + e1 + e2);
  const float w0 = e0 * inv_sum, w1 = e1 * inv_sum, w2 = e2 * inv_sum;
  const int c = t & 127;
  const int h = c >> 2;
  const bool is_re = (t < 128);
  const float th = theta[k * 128 + c];
  const size_t base = (size_t)blockIdx.x * 257;
  const float off_c = cs[base + t];
  const float den_off = cs[base + 256];
  __syncthreads();
  if (t < 64) {
    float v = pw_s[t];
#pragma unroll
    for (int off = 1; off < 64; off <<= 1) {
      float o = __shfl_up(v, off, 64);
      if (t >= off) v += o;
    }
    inv_s[t] = 1.f / fmaxf(den_off + v, 1e-4f);
  }
  __syncthreads();
  // --- phase A ---
  {
    float acc = 0.f;
    const int xoff = h * 68;
    for (int l4 = 0; l4 < CHUNK_L; l4 += 4) {
      ushort4 xr = *(const ushort4*)(xv_s + xoff + l4);
      float4 pw4 = *(const float4*)(pw_s + l4);
      float4 iv4 = *(const float4*)(inv_s + l4);
      const float xs[4] = {bf2f(xr.x), bf2f(xr.y), bf2f(xr.z), bf2f(xr.w)};
      const float ps[4] = {pw4.x, pw4.y, pw4.z, pw4.w};
      const float ivs[4] = {iv4.x, iv4.y, iv4.z, iv4.w};
#pragma unroll
      for (int j = 0; j < 4; j++) {
        const float xx = xs[j];
        const float phi = xx * th;
        const float poly = fmaf(-w2 * xx, xx, fmaf(w1, xx, w0));
        const float tr = is_re ? __cosf(phi) : __sinf(phi);
        acc = fmaf(ps[j] * poly, tr, acc);
        v_s[(l4 + j) * 264 + t] = f2bf((off_c + acc) * ivs[j]);
      }
    }
  }
  __syncthreads();
  // --- phase B ---
  {
    const int l = t >> 2, cg = t & 3;
    const ushort_t* vp = v_s + l * 264 + cg * 64;
    float s = 0.f;
#pragma unroll
    for (int i = 0; i < 64; i += 4) {
      ushort4 a = *(const ushort4*)(vp + i);
      const float f0 = bf2f(a.x), f1 = bf2f(a.y), f2v = bf2f(a.z), f3 = bf2f(a.w);
      s = fmaf(f0, f0, s);
      s = fmaf(f1, f1, s);
      s = fmaf(f2v, f2v, s);
      s = fmaf(f3, f3, s);
    }
    part_s[t] = s;
  }
  __syncthreads();
  if (t < 64) {
    float4 p = *(const float4*)(part_s + t * 4);
    rsq_s[t] = rsqrtf((p.x + p.y + p.z + p.w) * (1.f / 256.f) + 1e-5f);
  }
  __syncthreads();
  // --- phase C ---
  {
    const int wave = t >> 6, lane = t & 63;
    const int quad = lane >> 4, r16 = lane & 15;
    f32x4 acc0 = {}, acc1 = {};
    const int m_row = wave * 16 + r16;
    const ushort_t* wb0 = wtp + r16 * 256;
    const ushort_t* wb1 = wtp + (16 + r16) * 256;
#pragma unroll
    for (int kk = 0; kk < 8; kk++) {
      short8 af = *(const short8*)(v_s + m_row * 264 + kk * 32 + quad * 8);
      short8 b0 = *(const short8*)(wb0 + kk * 32 + quad * 8);
      short8 b1 = *(const short8*)(wb1 + kk * 32 + quad * 8);
      acc0 = __builtin_amdgcn_mfma_f32_16x16x32_bf16(af, b0, acc0, 0, 0, 0);
      acc1 = __builtin_amdgcn_mfma_f32_16x16x32_bf16(af, b1, acc1, 0, 0, 0);
    }
#pragma unroll
    for (int r = 0; r < 4; r++) {
      const int l = wave * 16 + quad * 4 + r;
      const float rs = rsq_s[l];
      const size_t row = (size_t)(b * L_SEQC + l0 + l) * D_MODELC + k * H_DIMC;
      const int h0 = r16, h1 = 16 + r16;
      ypre[row + h0] = f2bf(acc0[r] * rs * bf2f(gate[row + h0]));
      ypre[row + h1] = f2bf(acc1[r] * rs * bf2f(gate[row + h1]));
    }
  }
}

// ---------------------------------------------------------------------------
extern "C" void kernel_launch(void* const* d_in, const int* in_sizes, int n_in,
                              void* d_out, int out_size, void* d_ws, size_t ws_size,
                              hipStream_t stream) {
  const float* x       = (const float*)d_in[0];
  const float* W_in    = (const float*)d_in[1];
  const float* w_conv  = (const float*)d_in[2];
  const float* b_conv  = (const float*)d_in[3];
  const float* theta   = (const float*)d_in[4];
  const float* dec     = (const float*)d_in[5];
  const float* anc     = (const float*)d_in[6];
  const float* score   = (const float*)d_in[7];
  const float* dlog    = (const float*)d_in[8];
  const float* nsc     = (const float*)d_in[9];
  const float* W_re    = (const float*)d_in[10];
  const float* W_im    = (const float*)d_in[11];
  const float* W_out   = (const float*)d_in[12];
  float* out = (float*)d_out;

  char* wsb = (char*)d_ws;
  ushort_t* z    = (ushort_t*)(wsb + 0);          // bf16, 34,078,720 B
  ushort_t* ypre = (ushort_t*)(wsb + 0);          // alias (z dead), 16.8 MB
  ushort_t* WtO  = (ushort_t*)(wsb + 16777216);   // alias, 2 MB
  float*    cs   = (float*)(wsb + 20971520);      // alias, 4.2 MB
  ushort_t* wtp  = (ushort_t*)(wsb + 26214400);   // alias, 16 KB
  ushort_t* xv   = (ushort_t*)(wsb + 68157440);   // 16,777,216
  ushort_t* gate = (ushort_t*)(wsb + 84934656);   // 16,777,216
  float*    pwb  = (float*)(wsb + 101711872);     // 1,048,576
  ushort_t* xb   = (ushort_t*)(wsb + 102760448);  // 16,777,216
  ushort_t* WtI  = (ushort_t*)(wsb + 119537664);  // 4,456,448
  // total 123,994,112 B

  dim3 blk(256);
  const int M = B_SZC * L_SEQC;  // 8192

  cvt_bf16<<<dim3(M * D_MODELC / 1024), blk, 0, stream>>>(x, xb, M * D_MODELC);
  cvt_t_bf16<<<dim3(2176 / 32, D_MODELC / 32), blk, 0, stream>>>(
      W_in, WtI, D_MODELC, TOTALC, 2176);
  gemm_bf16_bt<true><<<dim3((2176 / 128) * (M / 128)), blk, 0, stream>>>(
      xb, WtI, z, M, D_MODELC, TOTALC, 2176 / 128);
  conv_act<<<dim3((B_SZC * L_SEQC * (TOTALC / 4) + 255) / 256), blk, 0, stream>>>(
      z, w_conv, b_conv, score, dec, anc, xv, gate, pwb);
  // z dead from here; WtO/cs/wtp/ypre alias its region
  cvt_t_bf16<<<dim3(D_MODELC / 32, D_MODELC / 32), blk, 0, stream>>>(
      W_out, WtO, D_MODELC, D_MODELC, D_MODELC);
  wt_pack<<<dim3(32), blk, 0, stream>>>(W_re, W_im, nsc, wtp);
  scan_partial<<<dim3(B_SZC * K_HEADSC * NCHUNK), blk, 0, stream>>>(
      xv, pwb, theta, dlog, cs);
  scan_chunks<<<dim3((B_SZC * K_HEADSC * 257 + 255) / 256), blk, 0, stream>>>(cs);
  scan_apply<<<dim3(B_SZC * K_HEADSC * NCHUNK), blk, 0, stream>>>(
      xv, pwb, gate, theta, dlog, wtp, cs, ypre);
  gemm_bf16_bt<false><<<dim3((D_MODELC / 128) * (M / 128)), blk, 0, stream>>>(
      ypre, WtO, out, M, D_MODELC, D_MODELC, D_MODELC / 128);
}

// Round 6
// 321.512 us; speedup vs baseline: 3.9617x; 1.0093x over previous
//
#include <hip/hip_runtime.h>
#include <math.h>

#define D_MODELC 1024
#define K_HEADSC 32
#define ANCHORC 4
#define M_THETAC 4
#define H_DIMC 32
#define TOTALC 2080
#define B_SZC 4
#define L_SEQC 2048
#define NCHUNK 32
#define CHUNK_L (L_SEQC / NCHUNK)  // 64

typedef unsigned short ushort_t;
typedef __attribute__((ext_vector_type(8))) short short8;
typedef __attribute__((ext_vector_type(4))) float f32x4;

__device__ __forceinline__ ushort_t f2bf(float f) {
  union { float f; unsigned u; } v; v.f = f;
  unsigned u = v.u;
  return (ushort_t)((u + 0x7fffu + ((u >> 16) & 1u)) >> 16);
}
__device__ __forceinline__ float bf2f(ushort_t b) {
  union { unsigned u; float f; } v; v.u = ((unsigned)b) << 16;
  return v.f;
}

// ---------------------------------------------------------------------------
// prep: fused x->bf16 cast, W_in^T, W_out^T, wt_pack (block-range dispatch)
//   blocks [0, 8192)          : cvt x (4 elems/thread)
//   blocks [8192, 10368)      : W_in transpose  (68 x 32 tile-blocks)
//   blocks [10368, 11392)     : W_out transpose (32 x 32 tile-blocks)
//   blocks [11392, 11424)     : wt_pack
// ---------------------------------------------------------------------------
__global__ __launch_bounds__(256) void prep(
    const float* __restrict__ x, const float* __restrict__ W_in,
    const float* __restrict__ W_out, const float* __restrict__ W_re,
    const float* __restrict__ W_im, const float* __restrict__ nsc,
    ushort_t* __restrict__ xb, ushort_t* __restrict__ WtI,
    ushort_t* __restrict__ WtO, ushort_t* __restrict__ wtp) {
  __shared__ float tile[32][33];
  const int bid = blockIdx.x;
  const int t = threadIdx.x;
  if (bid < 8192) {
    const int i = (bid * 256 + t) * 4;
    float4 v = *(const float4*)(x + i);
    ushort4 o = {f2bf(v.x), f2bf(v.y), f2bf(v.z), f2bf(v.w)};
    *(ushort4*)(xb + i) = o;
    return;
  }
  const float* W;
  ushort_t* Wt;
  int N, Npad, bx, by;
  if (bid < 10368) {
    const int bb = bid - 8192;
    W = W_in; Wt = WtI; N = TOTALC; Npad = 2176;
    bx = bb % 68; by = bb / 68;
  } else if (bid < 11392) {
    const int bb = bid - 10368;
    W = W_out; Wt = WtO; N = D_MODELC; Npad = D_MODELC;
    bx = bb % 32; by = bb / 32;
  } else {
    const int i = (bid - 11392) * 256 + t;
    const int h = i & 31, c = i >> 5;
    const float wv = ((c < 128) ? W_re[c * 32 + h] : W_im[(c - 128) * 32 + h]) * nsc[c];
    wtp[h * 256 + c] = f2bf(wv);
    return;
  }
  const int K = D_MODELC;
  const int n0 = bx * 32, k0 = by * 32;
  const int tx = t & 31, ty = t >> 5;
#pragma unroll
  for (int i = 0; i < 4; i++) {
    const int kk = ty + i * 8;
    const int n = n0 + tx;
    tile[kk][tx] = (n < N) ? W[(size_t)(k0 + kk) * N + n] : 0.f;
  }
  __syncthreads();
#pragma unroll
  for (int i = 0; i < 4; i++) {
    const int nn = ty + i * 8;
    Wt[(size_t)(n0 + nn) * K + k0 + tx] = f2bf(tile[tx][nn]);
  }
}

// ---------------------------------------------------------------------------
// bf16 MFMA GEMM: C[M,Nout] = A[M,K] @ Bt[N,K]^T  (out fp32 or bf16)
// BK=64, XOR-swizzled LDS: physical 16B-slot = row*8 + (colblk ^ (row&7)).
// Swizzle applied on the global source side (global_load_lds dest is fixed
// at base+lane*16), and mirrored on the ds_read side -> conflict-free b128.
// ---------------------------------------------------------------------------
template <bool OBF16>
__global__ __launch_bounds__(256) void gemm_bf16_bt(
    const ushort_t* __restrict__ A, const ushort_t* __restrict__ Bt,
    void* __restrict__ Cv, int M, int K, int Nout) {
  __shared__ ushort_t As[128 * 64];
  __shared__ ushort_t Bs[128 * 64];
  const int t = threadIdx.x;
  const int wave = t >> 6, lane = t & 63;
  const int m0 = blockIdx.y * 128, n0 = blockIdx.x * 128;
  const int m0w = (wave >> 1) * 64, n0w = (wave & 1) * 64;
  const int quad = lane >> 4, r16 = lane & 15;
  const int srow = lane >> 3;                    // 0..7 within segment
  const int scol = ((lane & 7) ^ srow) * 8;      // swizzled source column

  f32x4 acc[4][4] = {};

  for (int k0 = 0; k0 < K; k0 += 64) {
    __syncthreads();
#pragma unroll
    for (int i = 0; i < 4; i++) {
      const int seg = wave * 4 + i;              // 0..15, wave-uniform
      const int row = seg * 8 + srow;
      const ushort_t* gpA = A + (size_t)(m0 + row) * K + k0 + scol;
      const ushort_t* gpB = Bt + (size_t)(n0 + row) * K + k0 + scol;
      __builtin_amdgcn_global_load_lds(
          (const __attribute__((address_space(1))) void*)gpA,
          (__attribute__((address_space(3))) void*)(As + seg * 512), 16, 0, 0);
      __builtin_amdgcn_global_load_lds(
          (const __attribute__((address_space(1))) void*)gpB,
          (__attribute__((address_space(3))) void*)(Bs + seg * 512), 16, 0, 0);
    }
    __syncthreads();
#pragma unroll
    for (int kk = 0; kk < 2; kk++) {
      const int swz = ((kk * 4 + quad) ^ (r16 & 7)) * 8;
      short8 af[4], bfv[4];
#pragma unroll
      for (int i = 0; i < 4; i++)
        af[i] = *(const short8*)(As + (m0w + i * 16 + r16) * 64 + swz);
#pragma unroll
      for (int j = 0; j < 4; j++)
        bfv[j] = *(const short8*)(Bs + (n0w + j * 16 + r16) * 64 + swz);
#pragma unroll
      for (int i = 0; i < 4; i++)
#pragma unroll
        for (int j = 0; j < 4; j++)
          acc[i][j] = __builtin_amdgcn_mfma_f32_16x16x32_bf16(
              af[i], bfv[j], acc[i][j], 0, 0, 0);
    }
  }

#pragma unroll
  for (int i = 0; i < 4; i++) {
#pragma unroll
    for (int j = 0; j < 4; j++) {
      const int n = n0 + n0w + j * 16 + r16;
      if (n >= Nout) continue;
#pragma unroll
      for (int r = 0; r < 4; r++) {
        const int m = m0 + m0w + i * 16 + quad * 4 + r;
        if constexpr (OBF16) {
          ((ushort_t*)Cv)[(size_t)m * Nout + n] = f2bf(acc[i][j][r]);
        } else {
          ((float*)Cv)[(size_t)m * Nout + n] = acc[i][j][r];
        }
      }
    }
  }
}

// ---------------------------------------------------------------------------
// conv (causal depthwise k=4) on bf16 z, x4 vectorized; outputs xv/gate/pw
// ---------------------------------------------------------------------------
__global__ __launch_bounds__(256) void conv_act(
    const ushort_t* __restrict__ z, const float* __restrict__ wconv,
    const float* __restrict__ bconv, const float* __restrict__ score_scale,
    const float* __restrict__ dec_slopes, const float* __restrict__ anc_slopes,
    ushort_t* __restrict__ xv, ushort_t* __restrict__ gate,
    float* __restrict__ pw) {
  const int idx = blockIdx.x * 256 + threadIdx.x;
  if (idx >= B_SZC * L_SEQC * (TOTALC / 4)) return;
  const int c4 = (idx % (TOTALC / 4)) * 4;
  const int bl = idx / (TOTALC / 4);
  const int l = bl % L_SEQC;
  float4 bc = *(const float4*)(bconv + c4);
  float acc[4] = {bc.x, bc.y, bc.z, bc.w};
#pragma unroll
  for (int j = 0; j < 4; j++) {
    const int ls = l - 3 + j;
    if (ls >= 0) {
      ushort4 zr = *(const ushort4*)(z + (size_t)(bl - l + ls) * TOTALC + c4);
      float4 wc = *(const float4*)(wconv + j * TOTALC + c4);
      acc[0] = fmaf(bf2f(zr.x), wc.x, acc[0]);
      acc[1] = fmaf(bf2f(zr.y), wc.y, acc[1]);
      acc[2] = fmaf(bf2f(zr.z), wc.z, acc[2]);
      acc[3] = fmaf(bf2f(zr.w), wc.w, acc[3]);
    }
  }
  if (c4 < D_MODELC) {
    ushort4 o = {f2bf(acc[0]), f2bf(acc[1]), f2bf(acc[2]), f2bf(acc[3])};
    *(ushort4*)(xv + (size_t)bl * D_MODELC + c4) = o;
  } else if (c4 < 2 * D_MODELC) {
    ushort4 o;
    o.x = f2bf(acc[0] / (1.f + __expf(-acc[0])));
    o.y = f2bf(acc[1] / (1.f + __expf(-acc[1])));
    o.z = f2bf(acc[2] / (1.f + __expf(-acc[2])));
    o.w = f2bf(acc[3] / (1.f + __expf(-acc[3])));
    *(ushort4*)(gate + (size_t)bl * D_MODELC + (c4 - D_MODELC)) = o;
  } else {
    const int k0 = c4 - 2 * D_MODELC;  // 0,4,...,28 (group-uniform regime)
    float4 o;
    float* op = &o.x;
#pragma unroll
    for (int i = 0; i < 4; i++) {
      const int k = k0 + i;
      float sv = fminf(fmaxf(score_scale[k] * acc[i], -20.f), 20.f);
      float p = __expf(sv);
      float tw;
      if (k0 < K_HEADSC - ANCHORC) {
        float sd = log1pf(__expf(dec_slopes[k]));
        tw = __expf(-sd * (float)(L_SEQC - 1 - l));
      } else {
        float sa = log1pf(__expf(anc_slopes[k - (K_HEADSC - ANCHORC)]));
        tw = __expf(-sa * (float)l);
      }
      op[i] = p * tw;
    }
    *(float4*)(pw + (size_t)bl * K_HEADSC + k0) = o;
  }
}

// ---------------------------------------------------------------------------
// scan phase 1: per (b,k,chunk) sums of pw*poly*cos/sin (257 channels)
// ---------------------------------------------------------------------------
__global__ __launch_bounds__(256) void scan_partial(
    const ushort_t* __restrict__ xv, const float* __restrict__ pw,
    const float* __restrict__ theta, const float* __restrict__ dlog,
    float* __restrict__ cs) {
  const int t = threadIdx.x;
  const int chunk = blockIdx.x % NCHUNK;
  const int bk = blockIdx.x / NCHUNK;
  const int k = bk % K_HEADSC;
  const int b = bk / K_HEADSC;
  __shared__ __align__(16) ushort_t xv_s[32 * 68];
  __shared__ __align__(16) float pw_s[CHUNK_L];
  const int l0 = chunk * CHUNK_L;
  {
    const int h = t & 31, r0 = t >> 5;
#pragma unroll
    for (int rr = 0; rr < CHUNK_L / 8; rr++) {
      const int l = r0 + rr * 8;
      xv_s[h * 68 + l] = xv[(size_t)(b * L_SEQC + l0 + l) * D_MODELC + k * H_DIMC + h];
    }
  }
  if (t < CHUNK_L)
    pw_s[t] = pw[(size_t)(b * L_SEQC + l0 + t) * K_HEADSC + k];
  const float d0 = dlog[0], d1 = dlog[1], d2 = dlog[2];
  const float mx = fmaxf(d0, fmaxf(d1, d2));
  const float e0 = __expf(d0 - mx), e1 = __expf(d1 - mx), e2 = __expf(d2 - mx);
  const float inv_sum = 1.f / (e0 + e1 + e2);
  const float w0 = e0 * inv_sum, w1 = e1 * inv_sum, w2 = e2 * inv_sum;
  const int c = t & 127;
  const int h = c >> 2;
  const bool is_re = (t < 128);
  const float th = theta[k * 128 + c];
  __syncthreads();
  float acc = 0.f;
  const int xoff = h * 68;
  for (int l4 = 0; l4 < CHUNK_L; l4 += 4) {
    ushort4 xr = *(const ushort4*)(xv_s + xoff + l4);
    float4 pw4 = *(const float4*)(pw_s + l4);
    const float xs[4] = {bf2f(xr.x), bf2f(xr.y), bf2f(xr.z), bf2f(xr.w)};
    const float ps[4] = {pw4.x, pw4.y, pw4.z, pw4.w};
#pragma unroll
    for (int j = 0; j < 4; j++) {
      const float xx = xs[j];
      const float phi = xx * th;
      const float poly = fmaf(-w2 * xx, xx, fmaf(w1, xx, w0));
      const float tr = is_re ? __cosf(phi) : __sinf(phi);
      acc = fmaf(ps[j] * poly, tr, acc);
    }
  }
  const size_t base = (size_t)blockIdx.x * 257;
  cs[base + t] = acc;
  if (t == 0) {
    float s = 0.f;
    for (int l = 0; l < CHUNK_L; l++) s += pw_s[l];
    cs[base + 256] = s;
  }
}

// ---------------------------------------------------------------------------
// scan phase 2: exclusive scan over the NCHUNK chunk-sums per (b,k,channel)
// ---------------------------------------------------------------------------
__global__ __launch_bounds__(256) void scan_chunks(float* __restrict__ cs) {
  const int idx = blockIdx.x * 256 + threadIdx.x;
  if (idx >= B_SZC * K_HEADSC * 257) return;
  const int c = idx % 257;
  const int bk = idx / 257;
  float s = 0.f;
  for (int ch = 0; ch < NCHUNK; ++ch) {
    const size_t p = (size_t)(bk * NCHUNK + ch) * 257 + c;
    const float v = cs[p];
    cs[p] = s;
    s += v;
  }
}

// ---------------------------------------------------------------------------
// scan phase 3:
//  A: per-channel cumsum -> v (bf16) into LDS [64 l][264 c]
//  B: block sumsq for RMS
//  C: 64x256 @ 256x32 projection via MFMA (W frags from packed global table)
// ---------------------------------------------------------------------------
__global__ __launch_bounds__(256, 4) void scan_apply(
    const ushort_t* __restrict__ xv, const float* __restrict__ pw,
    const ushort_t* __restrict__ gate, const float* __restrict__ theta,
    const float* __restrict__ dlog, const ushort_t* __restrict__ wtp,
    const float* __restrict__ cs, ushort_t* __restrict__ ypre) {
  const int t = threadIdx.x;
  const int chunk = blockIdx.x % NCHUNK;
  const int bk = blockIdx.x / NCHUNK;
  const int k = bk % K_HEADSC;
  const int b = bk / K_HEADSC;
  __shared__ __align__(16) ushort_t xv_s[32 * 68];
  __shared__ __align__(16) float pw_s[CHUNK_L];
  __shared__ __align__(16) float inv_s[CHUNK_L];
  __shared__ __align__(16) ushort_t v_s[CHUNK_L * 264];
  __shared__ __align__(16) float part_s[256];
  __shared__ __align__(16) float rsq_s[CHUNK_L];

  const int l0 = chunk * CHUNK_L;
  {
    const int h = t & 31, r0 = t >> 5;
#pragma unroll
    for (int rr = 0; rr < CHUNK_L / 8; rr++) {
      const int l = r0 + rr * 8;
      xv_s[h * 68 + l] = xv[(size_t)(b * L_SEQC + l0 + l) * D_MODELC + k * H_DIMC + h];
    }
  }
  if (t < CHUNK_L)
    pw_s[t] = pw[(size_t)(b * L_SEQC + l0 + t) * K_HEADSC + k];
  const float d0 = dlog[0], d1 = dlog[1], d2 = dlog[2];
  const float mx = fmaxf(d0, fmaxf(d1, d2));
  const float e0 = __expf(d0 - mx), e1 = __expf(d1 - mx), e2 = __expf(d2 - mx);
  const float inv_sum = 1.f / (e0 + e1 + e2);
  const float w0 = e0 * inv_sum, w1 = e1 * inv_sum, w2 = e2 * inv_sum;
  const int c = t & 127;
  const int h = c >> 2;
  const bool is_re = (t < 128);
  const float th = theta[k * 128 + c];
  const size_t base = (size_t)blockIdx.x * 257;
  const float off_c = cs[base + t];
  const float den_off = cs[base + 256];
  __syncthreads();
  if (t < 64) {
    float v = pw_s[t];
#pragma unroll
    for (int off = 1; off < 64; off <<= 1) {
      float o = __shfl_up(v, off, 64);
      if (t >= off) v += o;
    }
    inv_s[t] = 1.f / fmaxf(den_off + v, 1e-4f);
  }
  __syncthreads();
  // --- phase A ---
  {
    float acc = 0.f;
    const int xoff = h * 68;
    for (int l4 = 0; l4 < CHUNK_L; l4 += 4) {
      ushort4 xr = *(const ushort4*)(xv_s + xoff + l4);
      float4 pw4 = *(const float4*)(pw_s + l4);
      float4 iv4 = *(const float4*)(inv_s + l4);
      const float xs[4] = {bf2f(xr.x), bf2f(xr.y), bf2f(xr.z), bf2f(xr.w)};
      const float ps[4] = {pw4.x, pw4.y, pw4.z, pw4.w};
      const float ivs[4] = {iv4.x, iv4.y, iv4.z, iv4.w};
#pragma unroll
      for (int j = 0; j < 4; j++) {
        const float xx = xs[j];
        const float phi = xx * th;
        const float poly = fmaf(-w2 * xx, xx, fmaf(w1, xx, w0));
        const float tr = is_re ? __cosf(phi) : __sinf(phi);
        acc = fmaf(ps[j] * poly, tr, acc);
        v_s[(l4 + j) * 264 + t] = f2bf((off_c + acc) * ivs[j]);
      }
    }
  }
  __syncthreads();
  // --- phase B ---
  {
    const int l = t >> 2, cg = t & 3;
    const ushort_t* vp = v_s + l * 264 + cg * 64;
    float s = 0.f;
#pragma unroll
    for (int i = 0; i < 64; i += 4) {
      ushort4 a = *(const ushort4*)(vp + i);
      const float f0 = bf2f(a.x), f1 = bf2f(a.y), f2v = bf2f(a.z), f3 = bf2f(a.w);
      s = fmaf(f0, f0, s);
      s = fmaf(f1, f1, s);
      s = fmaf(f2v, f2v, s);
      s = fmaf(f3, f3, s);
    }
    part_s[t] = s;
  }
  __syncthreads();
  if (t < 64) {
    float4 p = *(const float4*)(part_s + t * 4);
    rsq_s[t] = rsqrtf((p.x + p.y + p.z + p.w) * (1.f / 256.f) + 1e-5f);
  }
  __syncthreads();
  // --- phase C ---
  {
    const int wave = t >> 6, lane = t & 63;
    const int quad = lane >> 4, r16 = lane & 15;
    f32x4 acc0 = {}, acc1 = {};
    const int m_row = wave * 16 + r16;
    const ushort_t* wb0 = wtp + r16 * 256;
    const ushort_t* wb1 = wtp + (16 + r16) * 256;
#pragma unroll
    for (int kk = 0; kk < 8; kk++) {
      short8 af = *(const short8*)(v_s + m_row * 264 + kk * 32 + quad * 8);
      short8 b0 = *(const short8*)(wb0 + kk * 32 + quad * 8);
      short8 b1 = *(const short8*)(wb1 + kk * 32 + quad * 8);
      acc0 = __builtin_amdgcn_mfma_f32_16x16x32_bf16(af, b0, acc0, 0, 0, 0);
      acc1 = __builtin_amdgcn_mfma_f32_16x16x32_bf16(af, b1, acc1, 0, 0, 0);
    }
#pragma unroll
    for (int r = 0; r < 4; r++) {
      const int l = wave * 16 + quad * 4 + r;
      const float rs = rsq_s[l];
      const size_t row = (size_t)(b * L_SEQC + l0 + l) * D_MODELC + k * H_DIMC;
      const int h0 = r16, h1 = 16 + r16;
      ypre[row + h0] = f2bf(acc0[r] * rs * bf2f(gate[row + h0]));
      ypre[row + h1] = f2bf(acc1[r] * rs * bf2f(gate[row + h1]));
    }
  }
}

// ---------------------------------------------------------------------------
extern "C" void kernel_launch(void* const* d_in, const int* in_sizes, int n_in,
                              void* d_out, int out_size, void* d_ws, size_t ws_size,
                              hipStream_t stream) {
  const float* x       = (const float*)d_in[0];
  const float* W_in    = (const float*)d_in[1];
  const float* w_conv  = (const float*)d_in[2];
  const float* b_conv  = (const float*)d_in[3];
  const float* theta   = (const float*)d_in[4];
  const float* dec     = (const float*)d_in[5];
  const float* anc     = (const float*)d_in[6];
  const float* score   = (const float*)d_in[7];
  const float* dlog    = (const float*)d_in[8];
  const float* nsc     = (const float*)d_in[9];
  const float* W_re    = (const float*)d_in[10];
  const float* W_im    = (const float*)d_in[11];
  const float* W_out   = (const float*)d_in[12];
  float* out = (float*)d_out;

  char* wsb = (char*)d_ws;
  ushort_t* z    = (ushort_t*)(wsb + 0);          // bf16, 34,078,720 B
  ushort_t* ypre = (ushort_t*)(wsb + 0);          // alias (z dead), 16.8 MB
  float*    cs   = (float*)(wsb + 20971520);      // alias (z dead), 4.2 MB
  ushort_t* xv   = (ushort_t*)(wsb + 68157440);   // 16,777,216
  ushort_t* gate = (ushort_t*)(wsb + 84934656);   // 16,777,216
  float*    pwb  = (float*)(wsb + 101711872);     // 1,048,576
  ushort_t* xb   = (ushort_t*)(wsb + 102760448);  // 16,777,216
  ushort_t* WtI  = (ushort_t*)(wsb + 119537664);  // 4,456,448
  ushort_t* WtO  = (ushort_t*)(wsb + 123994112);  // 2,097,152 (NOT aliased: prep runs before gemm1)
  ushort_t* wtp  = (ushort_t*)(wsb + 126091264);  // 16,384
  // total 126,107,648 B

  dim3 blk(256);
  const int M = B_SZC * L_SEQC;  // 8192

  prep<<<dim3(11424), blk, 0, stream>>>(
      x, W_in, W_out, W_re, W_im, nsc, xb, WtI, WtO, wtp);
  gemm_bf16_bt<true><<<dim3(2176 / 128, M / 128), blk, 0, stream>>>(
      xb, WtI, z, M, D_MODELC, TOTALC);
  conv_act<<<dim3((B_SZC * L_SEQC * (TOTALC / 4) + 255) / 256), blk, 0, stream>>>(
      z, w_conv, b_conv, score, dec, anc, xv, gate, pwb);
  // z dead from here; cs/ypre alias its region
  scan_partial<<<dim3(B_SZC * K_HEADSC * NCHUNK), blk, 0, stream>>>(
      xv, pwb, theta, dlog, cs);
  scan_chunks<<<dim3((B_SZC * K_HEADSC * 257 + 255) / 256), blk, 0, stream>>>(cs);
  scan_apply<<<dim3(B_SZC * K_HEADSC * NCHUNK), blk, 0, stream>>>(
      xv, pwb, gate, theta, dlog, wtp, cs, ypre);
  gemm_bf16_bt<false><<<dim3(D_MODELC / 128, M / 128), blk, 0, stream>>>(
      ypre, WtO, out, M, D_MODELC, D_MODELC);
}

// Round 7
// 304.052 us; speedup vs baseline: 4.1892x; 1.0574x over previous
//
#include <hip/hip_runtime.h>
#include <math.h>

#define D_MODELC 1024
#define K_HEADSC 32
#define ANCHORC 4
#define M_THETAC 4
#define H_DIMC 32
#define TOTALC 2080
#define B_SZC 4
#define L_SEQC 2048
#define NCHUNK 32
#define CHUNK_L (L_SEQC / NCHUNK)  // 64
#define INV_2PI 0.15915494309189535f

typedef unsigned short ushort_t;
typedef __attribute__((ext_vector_type(8))) short short8;
typedef __attribute__((ext_vector_type(4))) float f32x4;

__device__ __forceinline__ ushort_t f2bf(float f) {
  union { float f; unsigned u; } v; v.f = f;
  unsigned u = v.u;
  return (ushort_t)((u + 0x7fffu + ((u >> 16) & 1u)) >> 16);
}
__device__ __forceinline__ ushort_t f2bf_fast(float f) {
  union { float f; unsigned u; } v; v.f = f;
  return (ushort_t)((v.u + 0x8000u) >> 16);
}
__device__ __forceinline__ float bf2f(ushort_t b) {
  union { unsigned u; float f; } v; v.u = ((unsigned)b) << 16;
  return v.f;
}

// ---------------------------------------------------------------------------
// prep: fused x->bf16 cast, W_in^T, W_out^T, wt_pack (block-range dispatch)
// ---------------------------------------------------------------------------
__global__ __launch_bounds__(256) void prep(
    const float* __restrict__ x, const float* __restrict__ W_in,
    const float* __restrict__ W_out, const float* __restrict__ W_re,
    const float* __restrict__ W_im, const float* __restrict__ nsc,
    ushort_t* __restrict__ xb, ushort_t* __restrict__ WtI,
    ushort_t* __restrict__ WtO, ushort_t* __restrict__ wtp) {
  __shared__ float tile[32][33];
  const int bid = blockIdx.x;
  const int t = threadIdx.x;
  if (bid < 8192) {
    const int i = (bid * 256 + t) * 4;
    float4 v = *(const float4*)(x + i);
    ushort4 o = {f2bf(v.x), f2bf(v.y), f2bf(v.z), f2bf(v.w)};
    *(ushort4*)(xb + i) = o;
    return;
  }
  const float* W;
  ushort_t* Wt;
  int N, bx, by;
  if (bid < 10368) {
    const int bb = bid - 8192;
    W = W_in; Wt = WtI; N = TOTALC;
    bx = bb % 68; by = bb / 68;
  } else if (bid < 11392) {
    const int bb = bid - 10368;
    W = W_out; Wt = WtO; N = D_MODELC;
    bx = bb % 32; by = bb / 32;
  } else {
    const int i = (bid - 11392) * 256 + t;
    const int h = i & 31, c = i >> 5;
    const float wv = ((c < 128) ? W_re[c * 32 + h] : W_im[(c - 128) * 32 + h]) * nsc[c];
    wtp[h * 256 + c] = f2bf(wv);
    return;
  }
  const int K = D_MODELC;
  const int n0 = bx * 32, k0 = by * 32;
  const int tx = t & 31, ty = t >> 5;
#pragma unroll
  for (int i = 0; i < 4; i++) {
    const int kk = ty + i * 8;
    const int n = n0 + tx;
    tile[kk][tx] = (n < N) ? W[(size_t)(k0 + kk) * N + n] : 0.f;
  }
  __syncthreads();
#pragma unroll
  for (int i = 0; i < 4; i++) {
    const int nn = ty + i * 8;
    Wt[(size_t)(n0 + nn) * K + k0 + tx] = f2bf(tile[tx][nn]);
  }
}

// ---------------------------------------------------------------------------
// bf16 MFMA GEMM: C[M,Nout] = A[M,K] @ Bt[N,K]^T  (out fp32 or bf16)
// BK=64, XOR-swizzled LDS (source-side swizzle for global_load_lds).
// ---------------------------------------------------------------------------
template <bool OBF16>
__global__ __launch_bounds__(256) void gemm_bf16_bt(
    const ushort_t* __restrict__ A, const ushort_t* __restrict__ Bt,
    void* __restrict__ Cv, int M, int K, int Nout) {
  __shared__ ushort_t As[128 * 64];
  __shared__ ushort_t Bs[128 * 64];
  const int t = threadIdx.x;
  const int wave = t >> 6, lane = t & 63;
  const int m0 = blockIdx.y * 128, n0 = blockIdx.x * 128;
  const int m0w = (wave >> 1) * 64, n0w = (wave & 1) * 64;
  const int quad = lane >> 4, r16 = lane & 15;
  const int srow = lane >> 3;
  const int scol = ((lane & 7) ^ srow) * 8;

  f32x4 acc[4][4] = {};

  for (int k0 = 0; k0 < K; k0 += 64) {
    __syncthreads();
#pragma unroll
    for (int i = 0; i < 4; i++) {
      const int seg = wave * 4 + i;
      const int row = seg * 8 + srow;
      const ushort_t* gpA = A + (size_t)(m0 + row) * K + k0 + scol;
      const ushort_t* gpB = Bt + (size_t)(n0 + row) * K + k0 + scol;
      __builtin_amdgcn_global_load_lds(
          (const __attribute__((address_space(1))) void*)gpA,
          (__attribute__((address_space(3))) void*)(As + seg * 512), 16, 0, 0);
      __builtin_amdgcn_global_load_lds(
          (const __attribute__((address_space(1))) void*)gpB,
          (__attribute__((address_space(3))) void*)(Bs + seg * 512), 16, 0, 0);
    }
    __syncthreads();
#pragma unroll
    for (int kk = 0; kk < 2; kk++) {
      const int swz = ((kk * 4 + quad) ^ (r16 & 7)) * 8;
      short8 af[4], bfv[4];
#pragma unroll
      for (int i = 0; i < 4; i++)
        af[i] = *(const short8*)(As + (m0w + i * 16 + r16) * 64 + swz);
#pragma unroll
      for (int j = 0; j < 4; j++)
        bfv[j] = *(const short8*)(Bs + (n0w + j * 16 + r16) * 64 + swz);
#pragma unroll
      for (int i = 0; i < 4; i++)
#pragma unroll
        for (int j = 0; j < 4; j++)
          acc[i][j] = __builtin_amdgcn_mfma_f32_16x16x32_bf16(
              af[i], bfv[j], acc[i][j], 0, 0, 0);
    }
  }

#pragma unroll
  for (int i = 0; i < 4; i++) {
#pragma unroll
    for (int j = 0; j < 4; j++) {
      const int n = n0 + n0w + j * 16 + r16;
      if (n >= Nout) continue;
#pragma unroll
      for (int r = 0; r < 4; r++) {
        const int m = m0 + m0w + i * 16 + quad * 4 + r;
        if constexpr (OBF16) {
          ((ushort_t*)Cv)[(size_t)m * Nout + n] = f2bf(acc[i][j][r]);
        } else {
          ((float*)Cv)[(size_t)m * Nout + n] = acc[i][j][r];
        }
      }
    }
  }
}

// ---------------------------------------------------------------------------
// conv (causal depthwise k=4) on bf16 z, x4 vectorized; outputs xv/gate/pw
// ---------------------------------------------------------------------------
__global__ __launch_bounds__(256) void conv_act(
    const ushort_t* __restrict__ z, const float* __restrict__ wconv,
    const float* __restrict__ bconv, const float* __restrict__ score_scale,
    const float* __restrict__ dec_slopes, const float* __restrict__ anc_slopes,
    ushort_t* __restrict__ xv, ushort_t* __restrict__ gate,
    float* __restrict__ pw) {
  const int idx = blockIdx.x * 256 + threadIdx.x;
  if (idx >= B_SZC * L_SEQC * (TOTALC / 4)) return;
  const int c4 = (idx % (TOTALC / 4)) * 4;
  const int bl = idx / (TOTALC / 4);
  const int l = bl % L_SEQC;
  float4 bc = *(const float4*)(bconv + c4);
  float acc[4] = {bc.x, bc.y, bc.z, bc.w};
#pragma unroll
  for (int j = 0; j < 4; j++) {
    const int ls = l - 3 + j;
    if (ls >= 0) {
      ushort4 zr = *(const ushort4*)(z + (size_t)(bl - l + ls) * TOTALC + c4);
      float4 wc = *(const float4*)(wconv + j * TOTALC + c4);
      acc[0] = fmaf(bf2f(zr.x), wc.x, acc[0]);
      acc[1] = fmaf(bf2f(zr.y), wc.y, acc[1]);
      acc[2] = fmaf(bf2f(zr.z), wc.z, acc[2]);
      acc[3] = fmaf(bf2f(zr.w), wc.w, acc[3]);
    }
  }
  if (c4 < D_MODELC) {
    ushort4 o = {f2bf(acc[0]), f2bf(acc[1]), f2bf(acc[2]), f2bf(acc[3])};
    *(ushort4*)(xv + (size_t)bl * D_MODELC + c4) = o;
  } else if (c4 < 2 * D_MODELC) {
    ushort4 o;
    o.x = f2bf(acc[0] / (1.f + __expf(-acc[0])));
    o.y = f2bf(acc[1] / (1.f + __expf(-acc[1])));
    o.z = f2bf(acc[2] / (1.f + __expf(-acc[2])));
    o.w = f2bf(acc[3] / (1.f + __expf(-acc[3])));
    *(ushort4*)(gate + (size_t)bl * D_MODELC + (c4 - D_MODELC)) = o;
  } else {
    const int k0 = c4 - 2 * D_MODELC;
    float4 o;
    float* op = &o.x;
#pragma unroll
    for (int i = 0; i < 4; i++) {
      const int k = k0 + i;
      float sv = fminf(fmaxf(score_scale[k] * acc[i], -20.f), 20.f);
      float p = __expf(sv);
      float tw;
      if (k0 < K_HEADSC - ANCHORC) {
        float sd = log1pf(__expf(dec_slopes[k]));
        tw = __expf(-sd * (float)(L_SEQC - 1 - l));
      } else {
        float sa = log1pf(__expf(anc_slopes[k - (K_HEADSC - ANCHORC)]));
        tw = __expf(-sa * (float)l);
      }
      op[i] = p * tw;
    }
    *(float4*)(pw + (size_t)bl * K_HEADSC + k0) = o;
  }
}

// ---------------------------------------------------------------------------
// scan phase 1: per (b,k,chunk) sums of pw*poly*cos/sin (257 channels)
// pp = pw*poly precomputed per (l,h); sin/cos in revolutions (scale folded
// into theta).
// ---------------------------------------------------------------------------
__global__ __launch_bounds__(256) void scan_partial(
    const ushort_t* __restrict__ xv, const float* __restrict__ pw,
    const float* __restrict__ theta, const float* __restrict__ dlog,
    float* __restrict__ cs) {
  const int t = threadIdx.x;
  const int chunk = blockIdx.x % NCHUNK;
  const int bk = blockIdx.x / NCHUNK;
  const int k = bk % K_HEADSC;
  const int b = bk / K_HEADSC;
  __shared__ __align__(16) ushort_t xv_s[32 * 68];
  __shared__ __align__(16) float pp_s[32 * 68];
  __shared__ __align__(16) float pw_s[CHUNK_L];
  const int l0 = chunk * CHUNK_L;
  const int hld = t & 31, r0 = t >> 5;
  {
#pragma unroll
    for (int rr = 0; rr < CHUNK_L / 8; rr++) {
      const int l = r0 + rr * 8;
      xv_s[hld * 68 + l] = xv[(size_t)(b * L_SEQC + l0 + l) * D_MODELC + k * H_DIMC + hld];
    }
  }
  if (t < CHUNK_L)
    pw_s[t] = pw[(size_t)(b * L_SEQC + l0 + t) * K_HEADSC + k];
  const float d0 = dlog[0], d1 = dlog[1], d2 = dlog[2];
  const float mx = fmaxf(d0, fmaxf(d1, d2));
  const float e0 = __expf(d0 - mx), e1 = __expf(d1 - mx), e2 = __expf(d2 - mx);
  const float inv_sum = 1.f / (e0 + e1 + e2);
  const float w0 = e0 * inv_sum, w1 = e1 * inv_sum, w2 = e2 * inv_sum;
  const int c = t & 127;
  const int h = c >> 2;
  const bool is_re = (t < 128);
  const float th_rev = theta[k * 128 + c] * INV_2PI;
  __syncthreads();
  // precompute pp = pw * poly per (l,h)
  {
#pragma unroll
    for (int rr = 0; rr < CHUNK_L / 8; rr++) {
      const int l = r0 + rr * 8;
      const float xx = bf2f(xv_s[hld * 68 + l]);
      const float poly = fmaf(-w2 * xx, xx, fmaf(w1, xx, w0));
      pp_s[hld * 68 + l] = pw_s[l] * poly;
    }
  }
  __syncthreads();
  float acc = 0.f;
  const int xoff = h * 68;
  for (int l4 = 0; l4 < CHUNK_L; l4 += 4) {
    ushort4 xr = *(const ushort4*)(xv_s + xoff + l4);
    float4 pr = *(const float4*)(pp_s + xoff + l4);
    const float xs[4] = {bf2f(xr.x), bf2f(xr.y), bf2f(xr.z), bf2f(xr.w)};
    const float ps[4] = {pr.x, pr.y, pr.z, pr.w};
#pragma unroll
    for (int j = 0; j < 4; j++) {
      const float phi = xs[j] * th_rev;
      const float tr = is_re ? __builtin_amdgcn_cosf(phi) : __builtin_amdgcn_sinf(phi);
      acc = fmaf(ps[j], tr, acc);
    }
  }
  const size_t base = (size_t)blockIdx.x * 257;
  cs[base + t] = acc;
  if (t == 0) {
    float s = 0.f;
    for (int l = 0; l < CHUNK_L; l++) s += pw_s[l];
    cs[base + 256] = s;
  }
}

// ---------------------------------------------------------------------------
// scan phase 2: exclusive scan over the NCHUNK chunk-sums per (b,k,channel)
// ---------------------------------------------------------------------------
__global__ __launch_bounds__(256) void scan_chunks(float* __restrict__ cs) {
  const int idx = blockIdx.x * 256 + threadIdx.x;
  if (idx >= B_SZC * K_HEADSC * 257) return;
  const int c = idx % 257;
  const int bk = idx / 257;
  float s = 0.f;
  for (int ch = 0; ch < NCHUNK; ++ch) {
    const size_t p = (size_t)(bk * NCHUNK + ch) * 257 + c;
    const float v = cs[p];
    cs[p] = s;
    s += v;
  }
}

// ---------------------------------------------------------------------------
// scan phase 3:
//  A: per-channel cumsum (acc init = chunk offset) -> v (bf16) in LDS
//  B: block sumsq for RMS
//  C: 64x256 @ 256x32 projection via MFMA; rsq+gate in epilogue
// ---------------------------------------------------------------------------
__global__ __launch_bounds__(256, 3) void scan_apply(
    const ushort_t* __restrict__ xv, const float* __restrict__ pw,
    const ushort_t* __restrict__ gate, const float* __restrict__ theta,
    const float* __restrict__ dlog, const ushort_t* __restrict__ wtp,
    const float* __restrict__ cs, ushort_t* __restrict__ ypre) {
  const int t = threadIdx.x;
  const int chunk = blockIdx.x % NCHUNK;
  const int bk = blockIdx.x / NCHUNK;
  const int k = bk % K_HEADSC;
  const int b = bk / K_HEADSC;
  __shared__ __align__(16) ushort_t xv_s[32 * 68];
  __shared__ __align__(16) float pp_s[32 * 68];
  __shared__ __align__(16) float pw_s[CHUNK_L];
  __shared__ __align__(16) float inv_s[CHUNK_L];
  __shared__ __align__(16) ushort_t v_s[CHUNK_L * 264];
  __shared__ __align__(16) float part_s[256];
  __shared__ __align__(16) float rsq_s[CHUNK_L];

  const int l0 = chunk * CHUNK_L;
  const int hld = t & 31, r0 = t >> 5;
  {
#pragma unroll
    for (int rr = 0; rr < CHUNK_L / 8; rr++) {
      const int l = r0 + rr * 8;
      xv_s[hld * 68 + l] = xv[(size_t)(b * L_SEQC + l0 + l) * D_MODELC + k * H_DIMC + hld];
    }
  }
  if (t < CHUNK_L)
    pw_s[t] = pw[(size_t)(b * L_SEQC + l0 + t) * K_HEADSC + k];
  const float d0 = dlog[0], d1 = dlog[1], d2 = dlog[2];
  const float mx = fmaxf(d0, fmaxf(d1, d2));
  const float e0 = __expf(d0 - mx), e1 = __expf(d1 - mx), e2 = __expf(d2 - mx);
  const float inv_sum = 1.f / (e0 + e1 + e2);
  const float w0 = e0 * inv_sum, w1 = e1 * inv_sum, w2 = e2 * inv_sum;
  const int c = t & 127;
  const int h = c >> 2;
  const bool is_re = (t < 128);
  const float th_rev = theta[k * 128 + c] * INV_2PI;
  const size_t base = (size_t)blockIdx.x * 257;
  const float off_c = cs[base + t];
  const float den_off = cs[base + 256];
  __syncthreads();
  // pp precompute (all threads) + inv scan (wave 0)
  {
#pragma unroll
    for (int rr = 0; rr < CHUNK_L / 8; rr++) {
      const int l = r0 + rr * 8;
      const float xx = bf2f(xv_s[hld * 68 + l]);
      const float poly = fmaf(-w2 * xx, xx, fmaf(w1, xx, w0));
      pp_s[hld * 68 + l] = pw_s[l] * poly;
    }
  }
  if (t < 64) {
    float v = pw_s[t];
#pragma unroll
    for (int off = 1; off < 64; off <<= 1) {
      float o = __shfl_up(v, off, 64);
      if (t >= off) v += o;
    }
    inv_s[t] = 1.f / fmaxf(den_off + v, 1e-4f);
  }
  __syncthreads();
  // --- phase A ---
  {
    float acc = off_c;
    const int xoff = h * 68;
    for (int l4 = 0; l4 < CHUNK_L; l4 += 4) {
      ushort4 xr = *(const ushort4*)(xv_s + xoff + l4);
      float4 pr = *(const float4*)(pp_s + xoff + l4);
      float4 iv4 = *(const float4*)(inv_s + l4);
      const float xs[4] = {bf2f(xr.x), bf2f(xr.y), bf2f(xr.z), bf2f(xr.w)};
      const float ps[4] = {pr.x, pr.y, pr.z, pr.w};
      const float ivs[4] = {iv4.x, iv4.y, iv4.z, iv4.w};
#pragma unroll
      for (int j = 0; j < 4; j++) {
        const float phi = xs[j] * th_rev;
        const float tr = is_re ? __builtin_amdgcn_cosf(phi) : __builtin_amdgcn_sinf(phi);
        acc = fmaf(ps[j], tr, acc);
        v_s[(l4 + j) * 264 + t] = f2bf_fast(acc * ivs[j]);
      }
    }
  }
  __syncthreads();
  // --- phase B ---
  {
    const int l = t >> 2, cg = t & 3;
    const ushort_t* vp = v_s + l * 264 + cg * 64;
    float s = 0.f;
#pragma unroll
    for (int i = 0; i < 64; i += 4) {
      ushort4 a = *(const ushort4*)(vp + i);
      const float f0 = bf2f(a.x), f1 = bf2f(a.y), f2v = bf2f(a.z), f3 = bf2f(a.w);
      s = fmaf(f0, f0, s);
      s = fmaf(f1, f1, s);
      s = fmaf(f2v, f2v, s);
      s = fmaf(f3, f3, s);
    }
    part_s[t] = s;
  }
  __syncthreads();
  if (t < 64) {
    float4 p = *(const float4*)(part_s + t * 4);
    rsq_s[t] = rsqrtf((p.x + p.y + p.z + p.w) * (1.f / 256.f) + 1e-5f);
  }
  __syncthreads();
  // --- phase C ---
  {
    const int wave = t >> 6, lane = t & 63;
    const int quad = lane >> 4, r16 = lane & 15;
    f32x4 acc0 = {}, acc1 = {};
    const int m_row = wave * 16 + r16;
    const ushort_t* wb0 = wtp + r16 * 256;
    const ushort_t* wb1 = wtp + (16 + r16) * 256;
#pragma unroll
    for (int kk = 0; kk < 8; kk++) {
      short8 af = *(const short8*)(v_s + m_row * 264 + kk * 32 + quad * 8);
      short8 b0 = *(const short8*)(wb0 + kk * 32 + quad * 8);
      short8 b1 = *(const short8*)(wb1 + kk * 32 + quad * 8);
      acc0 = __builtin_amdgcn_mfma_f32_16x16x32_bf16(af, b0, acc0, 0, 0, 0);
      acc1 = __builtin_amdgcn_mfma_f32_16x16x32_bf16(af, b1, acc1, 0, 0, 0);
    }
#pragma unroll
    for (int r = 0; r < 4; r++) {
      const int l = wave * 16 + quad * 4 + r;
      const float rs = rsq_s[l];
      const size_t row = (size_t)(b * L_SEQC + l0 + l) * D_MODELC + k * H_DIMC;
      const int h0 = r16, h1 = 16 + r16;
      ypre[row + h0] = f2bf(acc0[r] * rs * bf2f(gate[row + h0]));
      ypre[row + h1] = f2bf(acc1[r] * rs * bf2f(gate[row + h1]));
    }
  }
}

// ---------------------------------------------------------------------------
extern "C" void kernel_launch(void* const* d_in, const int* in_sizes, int n_in,
                              void* d_out, int out_size, void* d_ws, size_t ws_size,
                              hipStream_t stream) {
  const float* x       = (const float*)d_in[0];
  const float* W_in    = (const float*)d_in[1];
  const float* w_conv  = (const float*)d_in[2];
  const float* b_conv  = (const float*)d_in[3];
  const float* theta   = (const float*)d_in[4];
  const float* dec     = (const float*)d_in[5];
  const float* anc     = (const float*)d_in[6];
  const float* score   = (const float*)d_in[7];
  const float* dlog    = (const float*)d_in[8];
  const float* nsc     = (const float*)d_in[9];
  const float* W_re    = (const float*)d_in[10];
  const float* W_im    = (const float*)d_in[11];
  const float* W_out   = (const float*)d_in[12];
  float* out = (float*)d_out;

  char* wsb = (char*)d_ws;
  ushort_t* z    = (ushort_t*)(wsb + 0);          // bf16, 34,078,720 B
  ushort_t* ypre = (ushort_t*)(wsb + 0);          // alias (z dead), 16.8 MB
  float*    cs   = (float*)(wsb + 20971520);      // alias (z dead), 4.2 MB
  ushort_t* xv   = (ushort_t*)(wsb + 68157440);   // 16,777,216
  ushort_t* gate = (ushort_t*)(wsb + 84934656);   // 16,777,216
  float*    pwb  = (float*)(wsb + 101711872);     // 1,048,576
  ushort_t* xb   = (ushort_t*)(wsb + 102760448);  // 16,777,216
  ushort_t* WtI  = (ushort_t*)(wsb + 119537664);  // 4,456,448
  ushort_t* WtO  = (ushort_t*)(wsb + 123994112);  // 2,097,152
  ushort_t* wtp  = (ushort_t*)(wsb + 126091264);  // 16,384
  // total 126,107,648 B

  dim3 blk(256);
  const int M = B_SZC * L_SEQC;  // 8192

  prep<<<dim3(11424), blk, 0, stream>>>(
      x, W_in, W_out, W_re, W_im, nsc, xb, WtI, WtO, wtp);
  gemm_bf16_bt<true><<<dim3(2176 / 128, M / 128), blk, 0, stream>>>(
      xb, WtI, z, M, D_MODELC, TOTALC);
  conv_act<<<dim3((B_SZC * L_SEQC * (TOTALC / 4) + 255) / 256), blk, 0, stream>>>(
      z, w_conv, b_conv, score, dec, anc, xv, gate, pwb);
  // z dead from here; cs/ypre alias its region
  scan_partial<<<dim3(B_SZC * K_HEADSC * NCHUNK), blk, 0, stream>>>(
      xv, pwb, theta, dlog, cs);
  scan_chunks<<<dim3((B_SZC * K_HEADSC * 257 + 255) / 256), blk, 0, stream>>>(cs);
  scan_apply<<<dim3(B_SZC * K_HEADSC * NCHUNK), blk, 0, stream>>>(
      xv, pwb, gate, theta, dlog, wtp, cs, ypre);
  gemm_bf16_bt<false><<<dim3(D_MODELC / 128, M / 128), blk, 0, stream>>>(
      ypre, WtO, out, M, D_MODELC, D_MODELC);
}

// Round 8
// 297.354 us; speedup vs baseline: 4.2835x; 1.0225x over previous
//
#include <hip/hip_runtime.h>
#include <math.h>

#define D_MODELC 1024
#define K_HEADSC 32
#define ANCHORC 4
#define M_THETAC 4
#define H_DIMC 32
#define TOTALC 2080
#define B_SZC 4
#define L_SEQC 2048
#define NCHUNK 32
#define CHUNK_L (L_SEQC / NCHUNK)  // 64
#define INV_2PI 0.15915494309189535f

typedef unsigned short ushort_t;
typedef __attribute__((ext_vector_type(8))) short short8;
typedef __attribute__((ext_vector_type(4))) float f32x4;

__device__ __forceinline__ ushort_t f2bf(float f) {
  union { float f; unsigned u; } v; v.f = f;
  unsigned u = v.u;
  return (ushort_t)((u + 0x7fffu + ((u >> 16) & 1u)) >> 16);
}
__device__ __forceinline__ ushort_t f2bf_fast(float f) {
  union { float f; unsigned u; } v; v.f = f;
  return (ushort_t)((v.u + 0x8000u) >> 16);
}
__device__ __forceinline__ float bf2f(ushort_t b) {
  union { unsigned u; float f; } v; v.u = ((unsigned)b) << 16;
  return v.f;
}

// ---------------------------------------------------------------------------
// prep: fused x->bf16 cast, W_in^T, W_out^T, wt_pack (block-range dispatch)
// ---------------------------------------------------------------------------
__global__ __launch_bounds__(256) void prep(
    const float* __restrict__ x, const float* __restrict__ W_in,
    const float* __restrict__ W_out, const float* __restrict__ W_re,
    const float* __restrict__ W_im, const float* __restrict__ nsc,
    ushort_t* __restrict__ xb, ushort_t* __restrict__ WtI,
    ushort_t* __restrict__ WtO, ushort_t* __restrict__ wtp) {
  __shared__ float tile[32][33];
  const int bid = blockIdx.x;
  const int t = threadIdx.x;
  if (bid < 8192) {
    const int i = (bid * 256 + t) * 4;
    float4 v = *(const float4*)(x + i);
    ushort4 o = {f2bf(v.x), f2bf(v.y), f2bf(v.z), f2bf(v.w)};
    *(ushort4*)(xb + i) = o;
    return;
  }
  const float* W;
  ushort_t* Wt;
  int N, bx, by;
  if (bid < 10368) {
    const int bb = bid - 8192;
    W = W_in; Wt = WtI; N = TOTALC;
    bx = bb % 68; by = bb / 68;
  } else if (bid < 11392) {
    const int bb = bid - 10368;
    W = W_out; Wt = WtO; N = D_MODELC;
    bx = bb % 32; by = bb / 32;
  } else {
    const int i = (bid - 11392) * 256 + t;
    const int h = i & 31, c = i >> 5;
    const float wv = ((c < 128) ? W_re[c * 32 + h] : W_im[(c - 128) * 32 + h]) * nsc[c];
    wtp[h * 256 + c] = f2bf(wv);
    return;
  }
  const int K = D_MODELC;
  const int n0 = bx * 32, k0 = by * 32;
  const int tx = t & 31, ty = t >> 5;
#pragma unroll
  for (int i = 0; i < 4; i++) {
    const int kk = ty + i * 8;
    const int n = n0 + tx;
    tile[kk][tx] = (n < N) ? W[(size_t)(k0 + kk) * N + n] : 0.f;
  }
  __syncthreads();
#pragma unroll
  for (int i = 0; i < 4; i++) {
    const int nn = ty + i * 8;
    Wt[(size_t)(n0 + nn) * K + k0 + tx] = f2bf(tile[tx][nn]);
  }
}

// ---------------------------------------------------------------------------
// bf16 MFMA GEMM: C[M,Nout] = A[M,K] @ Bt[N,K]^T  (out fp32 or bf16)
// BK=64, XOR-swizzled LDS (source-side swizzle for global_load_lds).
// ---------------------------------------------------------------------------
template <bool OBF16>
__global__ __launch_bounds__(256) void gemm_bf16_bt(
    const ushort_t* __restrict__ A, const ushort_t* __restrict__ Bt,
    void* __restrict__ Cv, int M, int K, int Nout) {
  __shared__ ushort_t As[128 * 64];
  __shared__ ushort_t Bs[128 * 64];
  const int t = threadIdx.x;
  const int wave = t >> 6, lane = t & 63;
  const int m0 = blockIdx.y * 128, n0 = blockIdx.x * 128;
  const int m0w = (wave >> 1) * 64, n0w = (wave & 1) * 64;
  const int quad = lane >> 4, r16 = lane & 15;
  const int srow = lane >> 3;
  const int scol = ((lane & 7) ^ srow) * 8;

  f32x4 acc[4][4] = {};

  for (int k0 = 0; k0 < K; k0 += 64) {
    __syncthreads();
#pragma unroll
    for (int i = 0; i < 4; i++) {
      const int seg = wave * 4 + i;
      const int row = seg * 8 + srow;
      const ushort_t* gpA = A + (size_t)(m0 + row) * K + k0 + scol;
      const ushort_t* gpB = Bt + (size_t)(n0 + row) * K + k0 + scol;
      __builtin_amdgcn_global_load_lds(
          (const __attribute__((address_space(1))) void*)gpA,
          (__attribute__((address_space(3))) void*)(As + seg * 512), 16, 0, 0);
      __builtin_amdgcn_global_load_lds(
          (const __attribute__((address_space(1))) void*)gpB,
          (__attribute__((address_space(3))) void*)(Bs + seg * 512), 16, 0, 0);
    }
    __syncthreads();
#pragma unroll
    for (int kk = 0; kk < 2; kk++) {
      const int swz = ((kk * 4 + quad) ^ (r16 & 7)) * 8;
      short8 af[4], bfv[4];
#pragma unroll
      for (int i = 0; i < 4; i++)
        af[i] = *(const short8*)(As + (m0w + i * 16 + r16) * 64 + swz);
#pragma unroll
      for (int j = 0; j < 4; j++)
        bfv[j] = *(const short8*)(Bs + (n0w + j * 16 + r16) * 64 + swz);
#pragma unroll
      for (int i = 0; i < 4; i++)
#pragma unroll
        for (int j = 0; j < 4; j++)
          acc[i][j] = __builtin_amdgcn_mfma_f32_16x16x32_bf16(
              af[i], bfv[j], acc[i][j], 0, 0, 0);
    }
  }

#pragma unroll
  for (int i = 0; i < 4; i++) {
#pragma unroll
    for (int j = 0; j < 4; j++) {
      const int n = n0 + n0w + j * 16 + r16;
      if (n >= Nout) continue;
#pragma unroll
      for (int r = 0; r < 4; r++) {
        const int m = m0 + m0w + i * 16 + quad * 4 + r;
        if constexpr (OBF16) {
          ((ushort_t*)Cv)[(size_t)m * Nout + n] = f2bf(acc[i][j][r]);
        } else {
          ((float*)Cv)[(size_t)m * Nout + n] = acc[i][j][r];
        }
      }
    }
  }
}

// ---------------------------------------------------------------------------
// conv (causal depthwise k=4): 4 sequence positions x 4 channels per thread.
// 7 z-row loads serve 4 outputs (taps overlap); slope math once per thread.
// ---------------------------------------------------------------------------
__global__ __launch_bounds__(256) void conv_act(
    const ushort_t* __restrict__ z, const float* __restrict__ wconv,
    const float* __restrict__ bconv, const float* __restrict__ score_scale,
    const float* __restrict__ dec_slopes, const float* __restrict__ anc_slopes,
    ushort_t* __restrict__ xv, ushort_t* __restrict__ gate,
    float* __restrict__ pw) {
  const int idx = blockIdx.x * 256 + threadIdx.x;
  if (idx >= (B_SZC * L_SEQC / 4) * (TOTALC / 4)) return;
  const int c4 = (idx % (TOTALC / 4)) * 4;
  const int bl0 = (idx / (TOTALC / 4)) * 4;  // 4 consecutive l, same b
  const int l0 = bl0 & (L_SEQC - 1);
  float4 bc = *(const float4*)(bconv + c4);
  float4 wc[4];
#pragma unroll
  for (int j = 0; j < 4; j++) wc[j] = *(const float4*)(wconv + j * TOTALC + c4);
  float zr[7][4];
#pragma unroll
  for (int r = 0; r < 7; r++) {
    const int ls = l0 - 3 + r;
    if (ls >= 0) {
      ushort4 zv = *(const ushort4*)(z + (size_t)(bl0 - 3 + r) * TOTALC + c4);
      zr[r][0] = bf2f(zv.x); zr[r][1] = bf2f(zv.y);
      zr[r][2] = bf2f(zv.z); zr[r][3] = bf2f(zv.w);
    } else {
      zr[r][0] = zr[r][1] = zr[r][2] = zr[r][3] = 0.f;
    }
  }
  float acc[4][4];
#pragma unroll
  for (int i = 0; i < 4; i++) {
    const float* b = &bc.x;
#pragma unroll
    for (int ch = 0; ch < 4; ch++) {
      float a = b[ch];
#pragma unroll
      for (int j = 0; j < 4; j++) a = fmaf(zr[i + j][ch], (&wc[j].x)[ch], a);
      acc[i][ch] = a;
    }
  }
  if (c4 < D_MODELC) {
#pragma unroll
    for (int i = 0; i < 4; i++) {
      ushort4 o = {f2bf(acc[i][0]), f2bf(acc[i][1]), f2bf(acc[i][2]), f2bf(acc[i][3])};
      *(ushort4*)(xv + (size_t)(bl0 + i) * D_MODELC + c4) = o;
    }
  } else if (c4 < 2 * D_MODELC) {
#pragma unroll
    for (int i = 0; i < 4; i++) {
      ushort4 o;
      o.x = f2bf(acc[i][0] / (1.f + __expf(-acc[i][0])));
      o.y = f2bf(acc[i][1] / (1.f + __expf(-acc[i][1])));
      o.z = f2bf(acc[i][2] / (1.f + __expf(-acc[i][2])));
      o.w = f2bf(acc[i][3] / (1.f + __expf(-acc[i][3])));
      *(ushort4*)(gate + (size_t)(bl0 + i) * D_MODELC + (c4 - D_MODELC)) = o;
    }
  } else {
    const int k0 = c4 - 2 * D_MODELC;  // 0,4,...,28 (regime uniform in group)
    float ss[4], sl[4];
#pragma unroll
    for (int i = 0; i < 4; i++) {
      const int k = k0 + i;
      ss[i] = score_scale[k];
      sl[i] = (k0 < K_HEADSC - ANCHORC)
                  ? log1pf(__expf(dec_slopes[k]))
                  : log1pf(__expf(anc_slopes[k - (K_HEADSC - ANCHORC)]));
    }
#pragma unroll
    for (int i = 0; i < 4; i++) {
      const int l = l0 + i;
      const float dist = (k0 < K_HEADSC - ANCHORC) ? (float)(L_SEQC - 1 - l) : (float)l;
      float4 o;
      float* op = &o.x;
#pragma unroll
      for (int j = 0; j < 4; j++) {
        float sv = fminf(fmaxf(ss[j] * acc[i][j], -20.f), 20.f);
        op[j] = __expf(sv) * __expf(-sl[j] * dist);
      }
      *(float4*)(pw + (size_t)(bl0 + i) * K_HEADSC + k0) = o;
    }
  }
}

// ---------------------------------------------------------------------------
// scan phase 1: per (b,k,chunk) sums of pw*poly*cos/sin (257 channels)
// pp = pw*poly in LDS (cheap here: total LDS ~13 KB); rev-scaled trig.
// ---------------------------------------------------------------------------
__global__ __launch_bounds__(256) void scan_partial(
    const ushort_t* __restrict__ xv, const float* __restrict__ pw,
    const float* __restrict__ theta, const float* __restrict__ dlog,
    float* __restrict__ cs) {
  const int t = threadIdx.x;
  const int chunk = blockIdx.x % NCHUNK;
  const int bk = blockIdx.x / NCHUNK;
  const int k = bk % K_HEADSC;
  const int b = bk / K_HEADSC;
  __shared__ __align__(16) ushort_t xv_s[32 * 68];
  __shared__ __align__(16) float pp_s[32 * 68];
  __shared__ __align__(16) float pw_s[CHUNK_L];
  const int l0 = chunk * CHUNK_L;
  const int hld = t & 31, r0 = t >> 5;
  {
#pragma unroll
    for (int rr = 0; rr < CHUNK_L / 8; rr++) {
      const int l = r0 + rr * 8;
      xv_s[hld * 68 + l] = xv[(size_t)(b * L_SEQC + l0 + l) * D_MODELC + k * H_DIMC + hld];
    }
  }
  if (t < CHUNK_L)
    pw_s[t] = pw[(size_t)(b * L_SEQC + l0 + t) * K_HEADSC + k];
  const float d0 = dlog[0], d1 = dlog[1], d2 = dlog[2];
  const float mx = fmaxf(d0, fmaxf(d1, d2));
  const float e0 = __expf(d0 - mx), e1 = __expf(d1 - mx), e2 = __expf(d2 - mx);
  const float inv_sum = 1.f / (e0 + e1 + e2);
  const float w0 = e0 * inv_sum, w1 = e1 * inv_sum, w2 = e2 * inv_sum;
  const int c = t & 127;
  const int h = c >> 2;
  const bool is_re = (t < 128);
  const float th_rev = theta[k * 128 + c] * INV_2PI;
  __syncthreads();
  {
#pragma unroll
    for (int rr = 0; rr < CHUNK_L / 8; rr++) {
      const int l = r0 + rr * 8;
      const float xx = bf2f(xv_s[hld * 68 + l]);
      const float poly = fmaf(-w2 * xx, xx, fmaf(w1, xx, w0));
      pp_s[hld * 68 + l] = pw_s[l] * poly;
    }
  }
  __syncthreads();
  float acc = 0.f;
  const int xoff = h * 68;
  for (int l4 = 0; l4 < CHUNK_L; l4 += 4) {
    ushort4 xr = *(const ushort4*)(xv_s + xoff + l4);
    float4 pr = *(const float4*)(pp_s + xoff + l4);
    const float xs[4] = {bf2f(xr.x), bf2f(xr.y), bf2f(xr.z), bf2f(xr.w)};
    const float ps[4] = {pr.x, pr.y, pr.z, pr.w};
#pragma unroll
    for (int j = 0; j < 4; j++) {
      const float phi = xs[j] * th_rev;
      const float tr = is_re ? __builtin_amdgcn_cosf(phi) : __builtin_amdgcn_sinf(phi);
      acc = fmaf(ps[j], tr, acc);
    }
  }
  const size_t base = (size_t)blockIdx.x * 257;
  cs[base + t] = acc;
  if (t == 0) {
    float s = 0.f;
    for (int l = 0; l < CHUNK_L; l++) s += pw_s[l];
    cs[base + 256] = s;
  }
}

// ---------------------------------------------------------------------------
// scan phase 2: exclusive scan over the NCHUNK chunk-sums per (b,k,channel)
// ---------------------------------------------------------------------------
__global__ __launch_bounds__(256) void scan_chunks(float* __restrict__ cs) {
  const int idx = blockIdx.x * 256 + threadIdx.x;
  if (idx >= B_SZC * K_HEADSC * 257) return;
  const int c = idx % 257;
  const int bk = idx / 257;
  float s = 0.f;
  for (int ch = 0; ch < NCHUNK; ++ch) {
    const size_t p = (size_t)(bk * NCHUNK + ch) * 257 + c;
    const float v = cs[p];
    cs[p] = s;
    s += v;
  }
}

// ---------------------------------------------------------------------------
// scan phase 3 (poly inline; LDS kept at 39.9 KB for 4 blocks/CU):
//  A: per-channel cumsum (acc init = chunk offset) -> v (bf16) in LDS
//  B: block sumsq for RMS
//  C: 64x256 @ 256x32 projection via MFMA; rsq+gate in epilogue
// ---------------------------------------------------------------------------
__global__ __launch_bounds__(256, 4) void scan_apply(
    const ushort_t* __restrict__ xv, const float* __restrict__ pw,
    const ushort_t* __restrict__ gate, const float* __restrict__ theta,
    const float* __restrict__ dlog, const ushort_t* __restrict__ wtp,
    const float* __restrict__ cs, ushort_t* __restrict__ ypre) {
  const int t = threadIdx.x;
  const int chunk = blockIdx.x % NCHUNK;
  const int bk = blockIdx.x / NCHUNK;
  const int k = bk % K_HEADSC;
  const int b = bk / K_HEADSC;
  __shared__ __align__(16) ushort_t xv_s[32 * 68];
  __shared__ __align__(16) float pw_s[CHUNK_L];
  __shared__ __align__(16) float inv_s[CHUNK_L];
  __shared__ __align__(16) ushort_t v_s[CHUNK_L * 264];
  __shared__ __align__(16) float part_s[256];
  __shared__ __align__(16) float rsq_s[CHUNK_L];

  const int l0 = chunk * CHUNK_L;
  const int hld = t & 31, r0 = t >> 5;
  {
#pragma unroll
    for (int rr = 0; rr < CHUNK_L / 8; rr++) {
      const int l = r0 + rr * 8;
      xv_s[hld * 68 + l] = xv[(size_t)(b * L_SEQC + l0 + l) * D_MODELC + k * H_DIMC + hld];
    }
  }
  if (t < CHUNK_L)
    pw_s[t] = pw[(size_t)(b * L_SEQC + l0 + t) * K_HEADSC + k];
  const float d0 = dlog[0], d1 = dlog[1], d2 = dlog[2];
  const float mx = fmaxf(d0, fmaxf(d1, d2));
  const float e0 = __expf(d0 - mx), e1 = __expf(d1 - mx), e2 = __expf(d2 - mx);
  const float inv_sum = 1.f / (e0 + e1 + e2);
  const float w0 = e0 * inv_sum, w1 = e1 * inv_sum, w2 = e2 * inv_sum;
  const int c = t & 127;
  const int h = c >> 2;
  const bool is_re = (t < 128);
  const float th_rev = theta[k * 128 + c] * INV_2PI;
  const size_t base = (size_t)blockIdx.x * 257;
  const float off_c = cs[base + t];
  const float den_off = cs[base + 256];
  __syncthreads();
  if (t < 64) {
    float v = pw_s[t];
#pragma unroll
    for (int off = 1; off < 64; off <<= 1) {
      float o = __shfl_up(v, off, 64);
      if (t >= off) v += o;
    }
    inv_s[t] = 1.f / fmaxf(den_off + v, 1e-4f);
  }
  __syncthreads();
  // --- phase A ---
  {
    float acc = off_c;
    const int xoff = h * 68;
    for (int l4 = 0; l4 < CHUNK_L; l4 += 4) {
      ushort4 xr = *(const ushort4*)(xv_s + xoff + l4);
      float4 pw4 = *(const float4*)(pw_s + l4);
      float4 iv4 = *(const float4*)(inv_s + l4);
      const float xs[4] = {bf2f(xr.x), bf2f(xr.y), bf2f(xr.z), bf2f(xr.w)};
      const float ps[4] = {pw4.x, pw4.y, pw4.z, pw4.w};
      const float ivs[4] = {iv4.x, iv4.y, iv4.z, iv4.w};
#pragma unroll
      for (int j = 0; j < 4; j++) {
        const float xx = xs[j];
        const float poly = fmaf(-w2 * xx, xx, fmaf(w1, xx, w0));
        const float phi = xx * th_rev;
        const float tr = is_re ? __builtin_amdgcn_cosf(phi) : __builtin_amdgcn_sinf(phi);
        acc = fmaf(ps[j] * poly, tr, acc);
        v_s[(l4 + j) * 264 + t] = f2bf_fast(acc * ivs[j]);
      }
    }
  }
  __syncthreads();
  // --- phase B ---
  {
    const int l = t >> 2, cg = t & 3;
    const ushort_t* vp = v_s + l * 264 + cg * 64;
    float s = 0.f;
#pragma unroll
    for (int i = 0; i < 64; i += 4) {
      ushort4 a = *(const ushort4*)(vp + i);
      const float f0 = bf2f(a.x), f1 = bf2f(a.y), f2v = bf2f(a.z), f3 = bf2f(a.w);
      s = fmaf(f0, f0, s);
      s = fmaf(f1, f1, s);
      s = fmaf(f2v, f2v, s);
      s = fmaf(f3, f3, s);
    }
    part_s[t] = s;
  }
  __syncthreads();
  if (t < 64) {
    float4 p = *(const float4*)(part_s + t * 4);
    rsq_s[t] = rsqrtf((p.x + p.y + p.z + p.w) * (1.f / 256.f) + 1e-5f);
  }
  __syncthreads();
  // --- phase C ---
  {
    const int wave = t >> 6, lane = t & 63;
    const int quad = lane >> 4, r16 = lane & 15;
    f32x4 acc0 = {}, acc1 = {};
    const int m_row = wave * 16 + r16;
    const ushort_t* wb0 = wtp + r16 * 256;
    const ushort_t* wb1 = wtp + (16 + r16) * 256;
#pragma unroll
    for (int kk = 0; kk < 8; kk++) {
      short8 af = *(const short8*)(v_s + m_row * 264 + kk * 32 + quad * 8);
      short8 b0 = *(const short8*)(wb0 + kk * 32 + quad * 8);
      short8 b1 = *(const short8*)(wb1 + kk * 32 + quad * 8);
      acc0 = __builtin_amdgcn_mfma_f32_16x16x32_bf16(af, b0, acc0, 0, 0, 0);
      acc1 = __builtin_amdgcn_mfma_f32_16x16x32_bf16(af, b1, acc1, 0, 0, 0);
    }
#pragma unroll
    for (int r = 0; r < 4; r++) {
      const int l = wave * 16 + quad * 4 + r;
      const float rs = rsq_s[l];
      const size_t row = (size_t)(b * L_SEQC + l0 + l) * D_MODELC + k * H_DIMC;
      const int h0 = r16, h1 = 16 + r16;
      ypre[row + h0] = f2bf(acc0[r] * rs * bf2f(gate[row + h0]));
      ypre[row + h1] = f2bf(acc1[r] * rs * bf2f(gate[row + h1]));
    }
  }
}

// ---------------------------------------------------------------------------
extern "C" void kernel_launch(void* const* d_in, const int* in_sizes, int n_in,
                              void* d_out, int out_size, void* d_ws, size_t ws_size,
                              hipStream_t stream) {
  const float* x       = (const float*)d_in[0];
  const float* W_in    = (const float*)d_in[1];
  const float* w_conv  = (const float*)d_in[2];
  const float* b_conv  = (const float*)d_in[3];
  const float* theta   = (const float*)d_in[4];
  const float* dec     = (const float*)d_in[5];
  const float* anc     = (const float*)d_in[6];
  const float* score   = (const float*)d_in[7];
  const float* dlog    = (const float*)d_in[8];
  const float* nsc     = (const float*)d_in[9];
  const float* W_re    = (const float*)d_in[10];
  const float* W_im    = (const float*)d_in[11];
  const float* W_out   = (const float*)d_in[12];
  float* out = (float*)d_out;

  char* wsb = (char*)d_ws;
  ushort_t* z    = (ushort_t*)(wsb + 0);          // bf16, 34,078,720 B
  ushort_t* ypre = (ushort_t*)(wsb + 0);          // alias (z dead), 16.8 MB
  float*    cs   = (float*)(wsb + 20971520);      // alias (z dead), 4.2 MB
  ushort_t* xv   = (ushort_t*)(wsb + 68157440);   // 16,777,216
  ushort_t* gate = (ushort_t*)(wsb + 84934656);   // 16,777,216
  float*    pwb  = (float*)(wsb + 101711872);     // 1,048,576
  ushort_t* xb   = (ushort_t*)(wsb + 102760448);  // 16,777,216
  ushort_t* WtI  = (ushort_t*)(wsb + 119537664);  // 4,456,448
  ushort_t* WtO  = (ushort_t*)(wsb + 123994112);  // 2,097,152
  ushort_t* wtp  = (ushort_t*)(wsb + 126091264);  // 16,384
  // total 126,107,648 B

  dim3 blk(256);
  const int M = B_SZC * L_SEQC;  // 8192

  prep<<<dim3(11424), blk, 0, stream>>>(
      x, W_in, W_out, W_re, W_im, nsc, xb, WtI, WtO, wtp);
  gemm_bf16_bt<true><<<dim3(2176 / 128, M / 128), blk, 0, stream>>>(
      xb, WtI, z, M, D_MODELC, TOTALC);
  conv_act<<<dim3(((B_SZC * L_SEQC / 4) * (TOTALC / 4) + 255) / 256), blk, 0, stream>>>(
      z, w_conv, b_conv, score, dec, anc, xv, gate, pwb);
  // z dead from here; cs/ypre alias its region
  scan_partial<<<dim3(B_SZC * K_HEADSC * NCHUNK), blk, 0, stream>>>(
      xv, pwb, theta, dlog, cs);
  scan_chunks<<<dim3((B_SZC * K_HEADSC * 257 + 255) / 256), blk, 0, stream>>>(cs);
  scan_apply<<<dim3(B_SZC * K_HEADSC * NCHUNK), blk, 0, stream>>>(
      xv, pwb, gate, theta, dlog, wtp, cs, ypre);
  gemm_bf16_bt<false><<<dim3(D_MODELC / 128, M / 128), blk, 0, stream>>>(
      ypre, WtO, out, M, D_MODELC, D_MODELC);
}